// Round 8
// baseline (473.195 us; speedup 1.0000x reference)
//
#include <hip/hip_runtime.h>
#include <hip/hip_bf16.h>

#define N_NODES  50000
#define N_EDGES  800000
#define N_GRAPHS 512
#define NTILES   3125   // N_NODES / 16
#define ETILES   50000  // N_EDGES / 16
#define CT       4      // edge tiles per wave chunk
#define NCHUNKS  (ETILES / CT)   // 12500

typedef short bf16x8 __attribute__((ext_vector_type(8)));
typedef float f32x4  __attribute__((ext_vector_type(4)));

// ---------------- workspace layout (BYTE offsets, 256-aligned) ----------------
constexpr size_t B_CNT  = 0;                 // N ints (zeroed)
constexpr size_t ZERO_BYTES = 200192;
constexpr size_t B_OFF  = 200192;            // (N+1) ints
constexpr size_t B_CUR  = 400384;            // N ints
constexpr size_t B_BSUM = 600576;            // 256 ints
constexpr size_t B_SEDGE= 601600;            // E int2 (src, eid) sorted by dst — 6.4 MB
constexpr size_t B_DSTA = 7001600;           // E ints: dst of sorted edge — 3.2 MB
constexpr size_t B_FR2  = 10201600;          // mlp MFMA frags, 43008 ushorts
constexpr size_t B_AGG  = 10287616;          // N*192 f (layer2); aliased as [N][96] (layer1)
constexpr size_t B_H1   = 48687616;          // N*64 f
constexpr size_t B_H2   = 61487616;          // N*64 f
constexpr size_t B_FOLD = 74287616;          // folded weights, 43424 floats
constexpr size_t B_FRAG = 74461440;          // bf16 edge-MFMA fragment weights (22528 ushorts)
// fold-region float offsets
constexpr int F_V1H = 0;      // [64][96]   V1[t][n]
constexpr int F_B1F = 6144;   // [96]
constexpr int F_V2H = 6240;   // [64][192]  V2[t][n]
constexpr int F_B2F = 18528;  // [192]
constexpr int F_U1  = 18720;  // [3][64][64]
constexpr int F_UB1 = 31008;  // [64]
constexpr int F_U2  = 31072;  // [3][64][64]
constexpr int F_UB2 = 43360;  // [64]
constexpr int FOLD_TOTAL = 43424;
// edge frag-region ushort offsets
constexpr int FR_W1E1 = 0;      // [4][64][8]   em1_w1^T A-frags (K padded 16->32)
constexpr int FR_W1E2 = 2048;   // [4][64][8]
constexpr int FR_V1   = 4096;   // [6][2][64][8]  V1 B-frags, k-permuted
constexpr int FR_V2   = 10240;  // [12][2][64][8] V2 B-frags, k-permuted
constexpr int FOLD2_TOTAL = 22528;
// mlp frag-region (fr2) ushort offsets
constexpr int FR3_M1W = 0;      // [3][4][64][8]     c1_w1^T A-frags (K=32)
constexpr int FR3_M1U = 6144;   // [3][4][2][64][8]  U1 B-frags, k-permuted
constexpr int FR3_M2W = 18432;  // [3][4][2][64][8]  c2_w1^T A-frags (K=64)
constexpr int FR3_M2U = 30720;  // [3][4][2][64][8]  U2 B-frags, k-permuted
constexpr int FOLD3_TOTAL = 43008;

__device__ inline unsigned short bf16u(float x) {
    unsigned int ua = __float_as_uint(x);
    return (unsigned short)((ua + 0x7FFFu + ((ua >> 16) & 1u)) >> 16);
}
__device__ inline unsigned int packbf2(float a, float b) {
    unsigned int ua = __float_as_uint(a), ub = __float_as_uint(b);
    return ((ua + 0x7FFFu + ((ua >> 16) & 1u)) >> 16) |
           ((ub + 0x7FFFu + ((ub >> 16) & 1u)) & 0xFFFF0000u);
}

// ---------------- fold: precompute folded weight products (fp32) ----------------
__global__ __launch_bounds__(256) void fold_kernel(
    const float* __restrict__ em1_w2, const float* __restrict__ em1_b2,
    const float* __restrict__ em2_w2, const float* __restrict__ em2_b2,
    const float* __restrict__ c1_lin_w, const float* __restrict__ c1_lin_b,
    const float* __restrict__ c2_lin_w, const float* __restrict__ c2_lin_b,
    const float* __restrict__ c1_w2, const float* __restrict__ c1_b2,
    const float* __restrict__ c2_w2, const float* __restrict__ c2_b2,
    const float* __restrict__ lin1_w, const float* __restrict__ lin1_b,
    const float* __restrict__ lin2_w, const float* __restrict__ lin2_b,
    float* __restrict__ fw)
{
    int idx = blockIdx.x * 256 + threadIdx.x;
    if (idx >= FOLD_TOTAL) return;
    int r = idx;
    if (r < 6144) {
        int k = r / 96, c = r % 96, i = c / 32, j = c % 32;
        float s = 0.f;
        for (int m = 0; m < 64; m++) s = fmaf(em1_w2[k * 64 + m], c1_lin_w[i * 2048 + m * 32 + j], s);
        fw[F_V1H + r] = s; return;
    }
    r -= 6144;
    if (r < 96) {
        int i = r / 32, j = r % 32;
        float s = c1_lin_b[r];
        for (int m = 0; m < 64; m++) s = fmaf(em1_b2[m], c1_lin_w[i * 2048 + m * 32 + j], s);
        fw[F_B1F + r] = s; return;
    }
    r -= 96;
    if (r < 12288) {
        int k = r / 192, c = r % 192, i = c / 64, j = c % 64;
        float s = 0.f;
        for (int m = 0; m < 64; m++) s = fmaf(em2_w2[k * 64 + m], c2_lin_w[i * 4096 + m * 64 + j], s);
        fw[F_V2H + r] = s; return;
    }
    r -= 12288;
    if (r < 192) {
        int i = r / 64, j = r % 64;
        float s = c2_lin_b[r];
        for (int m = 0; m < 64; m++) s = fmaf(em2_b2[m], c2_lin_w[i * 4096 + m * 64 + j], s);
        fw[F_B2F + r] = s; return;
    }
    r -= 192;
    if (r < 12288) {
        int i = r / 4096, k = (r / 64) % 64, j = r % 64;
        float s = 0.f;
        for (int m = 0; m < 64; m++) s = fmaf(c1_w2[i * 4096 + k * 64 + m], lin1_w[(i * 64 + m) * 64 + j], s);
        fw[F_U1 + r] = s; return;
    }
    r -= 12288;
    if (r < 64) {
        float s = lin1_b[r];
        for (int i = 0; i < 3; i++)
            for (int m = 0; m < 64; m++) s = fmaf(c1_b2[i * 64 + m], lin1_w[(i * 64 + m) * 64 + r], s);
        fw[F_UB1 + r] = s; return;
    }
    r -= 64;
    if (r < 12288) {
        int i = r / 4096, k = (r / 64) % 64, j = r % 64;
        float s = 0.f;
        for (int m = 0; m < 64; m++) s = fmaf(c2_w2[i * 4096 + k * 64 + m], lin2_w[(i * 64 + m) * 64 + j], s);
        fw[F_U2 + r] = s; return;
    }
    r -= 12288;
    {
        float s = lin2_b[r];
        for (int i = 0; i < 3; i++)
            for (int m = 0; m < 64; m++) s = fmaf(c2_b2[i * 64 + m], lin2_w[(i * 64 + m) * 64 + r], s);
        fw[F_UB2 + r] = s; return;
    }
}

// ---------------- fold2: edge-MFMA bf16 fragment weights ----------------
__global__ __launch_bounds__(256) void fold2_kernel(
    const float* __restrict__ em1_w1, const float* __restrict__ em2_w1,
    const float* __restrict__ fw, unsigned short* __restrict__ fr)
{
    int idx = blockIdx.x * 256 + threadIdx.x;
    if (idx >= FOLD2_TOTAL) return;
    if (idx < 4096) {
        const float* w = (idx < 2048) ? em1_w1 : em2_w1;
        int r = idx & 2047;
        int tt = r >> 9, lane = (r >> 3) & 63, j = r & 7;
        int q = lane >> 4, k = q * 8 + j, m = tt * 16 + (lane & 15);
        fr[idx] = (k < 16) ? bf16u(w[k * 64 + m]) : (unsigned short)0;
        return;
    }
    if (idx < 10240) {
        int r = idx - 4096;
        int nt = r / 1024, ka = (r >> 9) & 1, lane = (r >> 3) & 63, j = r & 7;
        int q = lane >> 4;
        int t = 32 * ka + 16 * (j >> 2) + 4 * q + (j & 3);
        int n = nt * 16 + (lane & 15);
        fr[idx] = bf16u(fw[F_V1H + t * 96 + n]);
        return;
    }
    {
        int r = idx - 10240;
        int nt = r / 1024, ka = (r >> 9) & 1, lane = (r >> 3) & 63, j = r & 7;
        int q = lane >> 4;
        int t = 32 * ka + 16 * (j >> 2) + 4 * q + (j & 3);
        int n = nt * 16 + (lane & 15);
        fr[idx] = bf16u(fw[F_V2H + t * 192 + n]);
        return;
    }
}

// ---------------- fold3: node-MLP MFMA fragments ----------------
__global__ __launch_bounds__(256) void fold3_kernel(
    const float* __restrict__ c1_w1, const float* __restrict__ c2_w1,
    const float* __restrict__ fw, unsigned short* __restrict__ fr2)
{
    int idx = blockIdx.x * 256 + threadIdx.x;
    if (idx >= FOLD3_TOTAL) return;
    if (idx < 6144) {
        int i = idx / 2048, r = idx % 2048;
        int tt = r >> 9, lane = (r >> 3) & 63, jj = r & 7;
        int k = (lane >> 4) * 8 + jj, m = tt * 16 + (lane & 15);
        fr2[FR3_M1W + idx] = bf16u(c1_w1[i * 2048 + k * 64 + m]);
        return;
    }
    if (idx < 18432) {
        int r = idx - 6144;
        int i = r / 4096, r2 = r % 4096;
        int b = r2 >> 10, ka = (r2 >> 9) & 1, lane = (r2 >> 3) & 63, jj = r2 & 7;
        int t = 32 * ka + 16 * (jj >> 2) + 4 * (lane >> 4) + (jj & 3);
        int n = b * 16 + (lane & 15);
        fr2[FR3_M1U + r] = bf16u(fw[F_U1 + i * 4096 + t * 64 + n]);
        return;
    }
    if (idx < 30720) {
        int r = idx - 18432;
        int i = r / 4096, r2 = r % 4096;
        int tt = r2 >> 10, ka = (r2 >> 9) & 1, lane = (r2 >> 3) & 63, jj = r2 & 7;
        int k = ka * 32 + (lane >> 4) * 8 + jj, m = tt * 16 + (lane & 15);
        fr2[FR3_M2W + r] = bf16u(c2_w1[i * 4096 + k * 64 + m]);
        return;
    }
    {
        int r = idx - 30720;
        int i = r / 4096, r2 = r % 4096;
        int b = r2 >> 10, ka = (r2 >> 9) & 1, lane = (r2 >> 3) & 63, jj = r2 & 7;
        int t = 32 * ka + 16 * (jj >> 2) + 4 * (lane >> 4) + (jj & 3);
        int n = b * 16 + (lane & 15);
        fr2[FR3_M2U + r] = bf16u(fw[F_U2 + i * 4096 + t * 64 + n]);
        return;
    }
}

// ---------------- counting sort: hist -> scan -> scatter ----------------
__global__ __launch_bounds__(256) void hist_kernel(const int* __restrict__ ei, int* __restrict__ cnt) {
    int e = blockIdx.x * 256 + threadIdx.x;
    if (e < N_EDGES) atomicAdd(&cnt[ei[N_EDGES + e]], 1);
}

__global__ __launch_bounds__(256) void scan1_kernel(const int* __restrict__ cnt,
                                                    int* __restrict__ off, int* __restrict__ bsum) {
    __shared__ int sh[256];
    int t = threadIdx.x, i = blockIdx.x * 256 + t;
    int v = (i < N_NODES) ? cnt[i] : 0;
    sh[t] = v; __syncthreads();
    for (int d = 1; d < 256; d <<= 1) {
        int add = (t >= d) ? sh[t - d] : 0;
        __syncthreads();
        sh[t] += add;
        __syncthreads();
    }
    if (i < N_NODES) off[i] = sh[t] - v;
    if (t == 255) bsum[blockIdx.x] = sh[255];
}

__global__ __launch_bounds__(256) void scan2_kernel(int* __restrict__ bsum) {
    __shared__ int sh[256];
    int t = threadIdx.x;
    int v = (t < 196) ? bsum[t] : 0;
    sh[t] = v; __syncthreads();
    for (int d = 1; d < 256; d <<= 1) {
        int add = (t >= d) ? sh[t - d] : 0;
        __syncthreads();
        sh[t] += add;
        __syncthreads();
    }
    bsum[t] = sh[t] - v;
}

__global__ __launch_bounds__(256) void scan3_kernel(int* __restrict__ off, const int* __restrict__ bsum,
                                                    int* __restrict__ cur) {
    int i = blockIdx.x * 256 + threadIdx.x;
    if (i < N_NODES) {
        int o = off[i] + bsum[i >> 8];
        off[i] = o;
        cur[i] = o;
    }
    if (i == 0) off[N_NODES] = N_EDGES;
}

// scatter also records dst per sorted slot (needed by fused gather for segment bounds)
__global__ __launch_bounds__(256) void scatter_kernel(const int* __restrict__ ei, int* __restrict__ cur,
                                                      int2* __restrict__ sedge, int* __restrict__ dsta) {
    int e = blockIdx.x * 256 + threadIdx.x;
    if (e >= N_EDGES) return;
    int d = ei[N_EDGES + e];
    int p = atomicAdd(&cur[d], 1);
    sedge[p] = make_int2(ei[e], e);
    dsta[p] = d;
}

// ---------------- FUSED edge-projection MFMA + segmented gather (v7) --------
// v6 counters: 95.7us, VALU 51%, bank-conflict 2.4M/dispatch. Remaining costs:
//  (a) packed-bf16 spill's quad-XOR pattern still 3-way conflicts on 4 banks
//      per (r,nt) (SW=97 wrap analysis), (b) manual RTNE packing ~9 VALU/value
//      (24 packs) + walk unpack ~5 VALU/step — all existing only to halve LDS,
//      which is NOT the limiting resource (25KB of 160KB).
// v7: plain fp32 spill for BOTH NT (SW=C+2; every LDS access lands 2 lanes/bank
// = free, no swizzle), walk reads floats directly; q2 no longer bf16-quantized.
// s_setprio(1) around MFMA clusters (no barriers here -> waves at independent
// phases, the regime where setprio paid +4-7% in m191).
// Kill-tells: VGPR->84 + FETCH explosion = regalloc spill; occupancy drop = LDS.
#define XLOAD(i) const float xv##i = X[(size_t)__builtin_amdgcn_readlane(se.x, i) * XD + xl];
#define WSTEP(i) { \
    const int dnn = __builtin_amdgcn_readlane(dv, i); \
    if (dnn != curd) { \
        if (curd >= 0) { do_flush(!inside); inside = true; } \
        curd = dnn; \
        acc0 = acc1 = acc2 = 0.f; \
    } \
    const int base = (i) * SW; \
    const float xe = xv##i; \
    acc0 += fmaxf(xe + Lf[base + lane], 0.f); \
    if constexpr (NT == 12) { \
        acc1 += fmaxf(xe + Lf[base + 64 + lane], 0.f); \
        acc2 += fmaxf(xe + Lf[base + 128 + lane], 0.f); \
    } else { \
        if (lane < 32) acc1 += fmaxf(xe + Lf[base + 64 + (lane & 31)], 0.f); \
    } \
}

template<int NT, int XD>
__global__ __launch_bounds__(256, 2) void fused_edge_gather(
    const float* __restrict__ edge_attr, const int2* __restrict__ sedge,
    const int* __restrict__ dsta,
    const unsigned short* __restrict__ w1frag, const float* __restrict__ b1,
    const unsigned short* __restrict__ vfrag,  const float* __restrict__ bias2,
    const float* __restrict__ X, float* __restrict__ agg, int nChunks)
{
    constexpr int C  = NT * 16;
    constexpr int SW = C + 2;           // fp32 words per edge row; SW%32==2 -> 2 lanes/bank everywhere
    __shared__ float lds[4 * 16 * SW];
    const int lane = threadIdx.x & 63;
    const int wid  = threadIdx.x >> 6;
    const int col  = lane & 15;
    const int quad = lane >> 4;
    const int cw   = blockIdx.x * 4 + wid;
    if (cw >= nChunks) return;
    float* Lf = lds + wid * 16 * SW;

    bf16x8 w1f[4];
#pragma unroll
    for (int tt = 0; tt < 4; tt++)
        w1f[tt] = *(const bf16x8*)(w1frag + (tt * 64 + lane) * 8);
    float4 b1v[4];
#pragma unroll
    for (int tt = 0; tt < 4; tt++)
        b1v[tt] = *(const float4*)(b1 + tt * 16 + quad * 4);
    float b2v[NT];
#pragma unroll
    for (int nt = 0; nt < NT; nt++) b2v[nt] = bias2[nt * 16 + col];

    const int xl = lane & (XD - 1);
    float acc0 = 0.f, acc1 = 0.f, acc2 = 0.f;
    int  curd  = -1;
    bool inside = false;

    auto do_flush = [&](bool atomicPath) {
        float* row = agg + (size_t)curd * C;
        if (!atomicPath) {
            row[lane] = acc0;
            if constexpr (NT == 12) { row[64 + lane] = acc1; row[128 + lane] = acc2; }
            else { if (lane < 32) row[64 + lane] = acc1; }
        } else {
            atomicAdd(&row[lane], acc0);
            if constexpr (NT == 12) { atomicAdd(&row[64 + lane], acc1); atomicAdd(&row[128 + lane], acc2); }
            else { if (lane < 32) atomicAdd(&row[64 + lane], acc1); }
        }
    };

    const int t0 = cw * CT;
    int2 se = sedge[(size_t)t0 * 16 + col];
    int  dv = dsta[(size_t)t0 * 16 + col];

    // ---- prologue: issue tile-0's scattered edge_attr raw loads ----
    float4 er0 = {0.f, 0.f, 0.f, 0.f}, er1 = {0.f, 0.f, 0.f, 0.f};
    if (quad < 2) {
        const int e0 = se.y;
        er0 = *(const float4*)(edge_attr + (size_t)e0 * 16 + quad * 8);
        er1 = *(const float4*)(edge_attr + (size_t)e0 * 16 + quad * 8 + 4);
    }

    for (int ti = 0; ti < CT; ++ti) {
        const int s = (t0 + ti) * 16 + col;

        // ---- prefetch next tile's edge metadata ----
        int2 se_n = se; int dv_n = dv;
        if (ti + 1 < CT) { se_n = sedge[s + 16]; dv_n = dsta[s + 16]; }

        // ---- 16 scattered X-row loads issued FIRST: in flight across MFMA A+B ----
        XLOAD(0)  XLOAD(1)  XLOAD(2)  XLOAD(3)
        XLOAD(4)  XLOAD(5)  XLOAD(6)  XLOAD(7)
        XLOAD(8)  XLOAD(9)  XLOAD(10) XLOAD(11)
        XLOAD(12) XLOAD(13) XLOAD(14) XLOAD(15)

        // ---- pack ea (waits only the ea loads — oldest outstanding) ----
        uint4 eau = make_uint4(0u, 0u, 0u, 0u);
        if (quad < 2) {
            eau.x = packbf2(er0.x, er0.y); eau.y = packbf2(er0.z, er0.w);
            eau.z = packbf2(er1.x, er1.y); eau.w = packbf2(er1.z, er1.w);
        }
        const bf16x8 eaf = __builtin_bit_cast(bf16x8, eau);

        // ---- edge MLP layer A ----
        __builtin_amdgcn_s_setprio(1);
        f32x4 c1[4];
#pragma unroll
        for (int tt = 0; tt < 4; tt++) {
            f32x4 ci = {b1v[tt].x, b1v[tt].y, b1v[tt].z, b1v[tt].w};
            c1[tt] = __builtin_amdgcn_mfma_f32_16x16x32_bf16(w1f[tt], eaf, ci, 0, 0, 0);
        }
        __builtin_amdgcn_s_setprio(0);
        bf16x8 a2[2];
#pragma unroll
        for (int ka = 0; ka < 2; ka++) {
            uint4 au;
            au.x = packbf2(fmaxf(c1[2 * ka][0], 0.f),     fmaxf(c1[2 * ka][1], 0.f));
            au.y = packbf2(fmaxf(c1[2 * ka][2], 0.f),     fmaxf(c1[2 * ka][3], 0.f));
            au.z = packbf2(fmaxf(c1[2 * ka + 1][0], 0.f), fmaxf(c1[2 * ka + 1][1], 0.f));
            au.w = packbf2(fmaxf(c1[2 * ka + 1][2], 0.f), fmaxf(c1[2 * ka + 1][3], 0.f));
            a2[ka] = __builtin_bit_cast(bf16x8, au);
        }

        // ---- edge MLP layer B, V-frags streamed; plain fp32 spill to LDS ----
        __builtin_amdgcn_s_setprio(1);
#pragma unroll
        for (int nt = 0; nt < NT; nt++) {
            const bf16x8 v0 = *(const bf16x8*)(vfrag + ((nt * 2 + 0) * 64 + lane) * 8);
            const bf16x8 v1 = *(const bf16x8*)(vfrag + ((nt * 2 + 1) * 64 + lane) * 8);
            f32x4 c = {b2v[nt], b2v[nt], b2v[nt], b2v[nt]};
            c = __builtin_amdgcn_mfma_f32_16x16x32_bf16(a2[0], v0, c, 0, 0, 0);
            c = __builtin_amdgcn_mfma_f32_16x16x32_bf16(a2[1], v1, c, 0, 0, 0);
#pragma unroll
            for (int r = 0; r < 4; r++)
                Lf[(quad * 4 + r) * SW + nt * 16 + col] = c[r];
        }
        __builtin_amdgcn_s_setprio(0);

        // ---- issue NEXT tile's edge_attr raw loads: covered by the walk ----
        if (ti + 1 < CT && quad < 2) {
            const int en = se_n.y;
            er0 = *(const float4*)(edge_attr + (size_t)en * 16 + quad * 8);
            er1 = *(const float4*)(edge_attr + (size_t)en * 16 + quad * 8 + 4);
        }

        // ---- segmented walk: pure fp32 LDS + VALU; dst via readlane (SALU) ----
        WSTEP(0)  WSTEP(1)  WSTEP(2)  WSTEP(3)
        WSTEP(4)  WSTEP(5)  WSTEP(6)  WSTEP(7)
        WSTEP(8)  WSTEP(9)  WSTEP(10) WSTEP(11)
        WSTEP(12) WSTEP(13) WSTEP(14) WSTEP(15)

        se = se_n; dv = dv_n;
    }
    do_flush(true);   // final open segment may continue into the next chunk
}
#undef XLOAD
#undef WSTEP

// ---------------- node MLP layer 1 via MFMA (16 nodes per wave) ----------------
__global__ __launch_bounds__(256) void mlp1_mfma_kernel(
    const float* __restrict__ x, const float* __restrict__ agg1,
    const unsigned short* __restrict__ fr2, const float* __restrict__ c1_b1,
    const float* __restrict__ fw, float* __restrict__ h1)
{
    const int lane = threadIdx.x & 63, wid = threadIdx.x >> 6;
    const int tile = blockIdx.x * 4 + wid;
    if (tile >= NTILES) return;
    const int col = lane & 15, quad = lane >> 4;
    const int node = tile * 16 + col;

    const float4 xa = *(const float4*)(x + (size_t)node * 32 + quad * 8);
    const float4 xb = *(const float4*)(x + (size_t)node * 32 + quad * 8 + 4);

    f32x4 c2[4];
#pragma unroll
    for (int b = 0; b < 4; b++) {
        const float ub = fw[F_UB1 + b * 16 + col];
        c2[b] = {ub, ub, ub, ub};
    }
#pragma unroll
    for (int i = 0; i < 3; i++) {
        const float4 a0 = *(const float4*)(agg1 + (size_t)node * 96 + i * 32 + quad * 8);
        const float4 a1 = *(const float4*)(agg1 + (size_t)node * 96 + i * 32 + quad * 8 + 4);
        uint4 iu;
        iu.x = packbf2(xa.x + a0.x, xa.y + a0.y);
        iu.y = packbf2(xa.z + a0.z, xa.w + a0.w);
        iu.z = packbf2(xb.x + a1.x, xb.y + a1.y);
        iu.w = packbf2(xb.z + a1.z, xb.w + a1.w);
        const bf16x8 inf = __builtin_bit_cast(bf16x8, iu);

        f32x4 c1[4];
#pragma unroll
        for (int tt = 0; tt < 4; tt++) {
            const bf16x8 wf = *(const bf16x8*)(fr2 + FR3_M1W + ((i * 4 + tt) * 64 + lane) * 8);
            const float4 bi = *(const float4*)(c1_b1 + i * 64 + tt * 16 + quad * 4);
            f32x4 ci = {bi.x, bi.y, bi.z, bi.w};
            c1[tt] = __builtin_amdgcn_mfma_f32_16x16x32_bf16(wf, inf, ci, 0, 0, 0);
        }
        bf16x8 a2[2];
#pragma unroll
        for (int ka = 0; ka < 2; ka++) {
            uint4 au;
            au.x = packbf2(fmaxf(c1[2 * ka][0], 0.f),     fmaxf(c1[2 * ka][1], 0.f));
            au.y = packbf2(fmaxf(c1[2 * ka][2], 0.f),     fmaxf(c1[2 * ka][3], 0.f));
            au.z = packbf2(fmaxf(c1[2 * ka + 1][0], 0.f), fmaxf(c1[2 * ka + 1][1], 0.f));
            au.w = packbf2(fmaxf(c1[2 * ka + 1][2], 0.f), fmaxf(c1[2 * ka + 1][3], 0.f));
            a2[ka] = __builtin_bit_cast(bf16x8, au);
        }
#pragma unroll
        for (int b = 0; b < 4; b++)
#pragma unroll
            for (int ka = 0; ka < 2; ka++) {
                const bf16x8 uf = *(const bf16x8*)(fr2 + FR3_M1U + (((i * 4 + b) * 2 + ka) * 64 + lane) * 8);
                c2[b] = __builtin_amdgcn_mfma_f32_16x16x32_bf16(a2[ka], uf, c2[b], 0, 0, 0);
            }
    }
    const int rowb = tile * 16 + quad * 4;
#pragma unroll
    for (int b = 0; b < 4; b++)
#pragma unroll
        for (int r = 0; r < 4; r++)
            h1[(size_t)(rowb + r) * 64 + b * 16 + col] = fmaxf(c2[b][r], 0.f);
}

// ---------------- node MLP layer 2 via MFMA (16 nodes per wave) ----------------
__global__ __launch_bounds__(256) void mlp2_mfma_kernel(
    const float* __restrict__ h1, const float* __restrict__ agg2,
    const unsigned short* __restrict__ fr2, const float* __restrict__ c2_b1,
    const float* __restrict__ fw, float* __restrict__ h2)
{
    const int lane = threadIdx.x & 63, wid = threadIdx.x >> 6;
    const int tile = blockIdx.x * 4 + wid;
    if (tile >= NTILES) return;
    const int col = lane & 15, quad = lane >> 4;
    const int node = tile * 16 + col;

    float4 hv[4];
#pragma unroll
    for (int p = 0; p < 4; p++)
        hv[p] = *(const float4*)(h1 + (size_t)node * 64 + (p >> 1) * 32 + quad * 8 + (p & 1) * 4);

    f32x4 c2[4];
#pragma unroll
    for (int b = 0; b < 4; b++) {
        const float ub = fw[F_UB2 + b * 16 + col];
        c2[b] = {ub, ub, ub, ub};
    }
#pragma unroll
    for (int i = 0; i < 3; i++) {
        bf16x8 inf[2];
#pragma unroll
        for (int ka = 0; ka < 2; ka++) {
            const float4 a0 = *(const float4*)(agg2 + (size_t)node * 192 + i * 64 + ka * 32 + quad * 8);
            const float4 a1 = *(const float4*)(agg2 + (size_t)node * 192 + i * 64 + ka * 32 + quad * 8 + 4);
            const float4 h0 = hv[ka * 2], h1v = hv[ka * 2 + 1];
            uint4 iu;
            iu.x = packbf2(h0.x + a0.x, h0.y + a0.y);
            iu.y = packbf2(h0.z + a0.z, h0.w + a0.w);
            iu.z = packbf2(h1v.x + a1.x, h1v.y + a1.y);
            iu.w = packbf2(h1v.z + a1.z, h1v.w + a1.w);
            inf[ka] = __builtin_bit_cast(bf16x8, iu);
        }
        f32x4 c1[4];
#pragma unroll
        for (int tt = 0; tt < 4; tt++) {
            const bf16x8 wf0 = *(const bf16x8*)(fr2 + FR3_M2W + (((i * 4 + tt) * 2 + 0) * 64 + lane) * 8);
            const bf16x8 wf1 = *(const bf16x8*)(fr2 + FR3_M2W + (((i * 4 + tt) * 2 + 1) * 64 + lane) * 8);
            const float4 bi = *(const float4*)(c2_b1 + i * 64 + tt * 16 + quad * 4);
            f32x4 ci = {bi.x, bi.y, bi.z, bi.w};
            ci = __builtin_amdgcn_mfma_f32_16x16x32_bf16(wf0, inf[0], ci, 0, 0, 0);
            c1[tt] = __builtin_amdgcn_mfma_f32_16x16x32_bf16(wf1, inf[1], ci, 0, 0, 0);
        }
        bf16x8 a2[2];
#pragma unroll
        for (int ka = 0; ka < 2; ka++) {
            uint4 au;
            au.x = packbf2(fmaxf(c1[2 * ka][0], 0.f),     fmaxf(c1[2 * ka][1], 0.f));
            au.y = packbf2(fmaxf(c1[2 * ka][2], 0.f),     fmaxf(c1[2 * ka][3], 0.f));
            au.z = packbf2(fmaxf(c1[2 * ka + 1][0], 0.f), fmaxf(c1[2 * ka + 1][1], 0.f));
            au.w = packbf2(fmaxf(c1[2 * ka + 1][2], 0.f), fmaxf(c1[2 * ka + 1][3], 0.f));
            a2[ka] = __builtin_bit_cast(bf16x8, au);
        }
#pragma unroll
        for (int b = 0; b < 4; b++)
#pragma unroll
            for (int ka = 0; ka < 2; ka++) {
                const bf16x8 uf = *(const bf16x8*)(fr2 + FR3_M2U + (((i * 4 + b) * 2 + ka) * 64 + lane) * 8);
                c2[b] = __builtin_amdgcn_mfma_f32_16x16x32_bf16(a2[ka], uf, c2[b], 0, 0, 0);
            }
    }
    const int rowb = tile * 16 + quad * 4;
#pragma unroll
    for (int b = 0; b < 4; b++)
#pragma unroll
        for (int r = 0; r < 4; r++)
            h2[(size_t)(rowb + r) * 64 + b * 16 + col] = fmaxf(c2[b][r], 0.f);
}

// ---------------- pooling + head (fused; batch is sorted) ----------------
__global__ __launch_bounds__(256) void pool_kernel(
    const float* __restrict__ h2, const int* __restrict__ batch,
    const float* __restrict__ u, const float* __restrict__ fc_w,
    const float* __restrict__ fc_b, float* __restrict__ out)
{
    __shared__ float red[256];
    const int g = blockIdx.x, t = threadIdx.x;
    int lo = 0, hi = N_NODES;
    while (lo < hi) { int m = (lo + hi) >> 1; if (batch[m] < g) lo = m + 1; else hi = m; }
    int lo2 = lo, hi2 = N_NODES;
    while (lo2 < hi2) { int m = (lo2 + hi2) >> 1; if (batch[m] < g + 1) lo2 = m + 1; else hi2 = m; }

    const int col = t & 63, ch = t >> 6;
    float s = 0.f;
    for (int idx = lo + ch; idx < lo2; idx += 4) s += h2[(size_t)idx * 64 + col];
    red[t] = s;
    __syncthreads();
    if (t < 64) red[t] = red[t] + red[64 + t] + red[128 + t] + red[192 + t];
    __syncthreads();
    if (t == 0) {
        const float inv = 1.f / fmaxf((float)(lo2 - lo), 1.f);
        float sv = fc_b[0];
        for (int j = 0; j < 64; j++) sv = fmaf(red[j] * inv, fc_w[j], sv);
        for (int k = 0; k < 32; k++) sv = fmaf(u[(size_t)g * 32 + k], fc_w[64 + k], sv);
        out[g] = sv;
    }
}

extern "C" void kernel_launch(void* const* d_in, const int* in_sizes, int n_in,
                              void* d_out, int out_size, void* d_ws, size_t ws_size,
                              hipStream_t stream) {
    (void)in_sizes; (void)n_in; (void)out_size; (void)ws_size;
    const float* x        = (const float*)d_in[0];
    const float* edge_attr= (const float*)d_in[1];
    const float* u        = (const float*)d_in[2];
    const float* em1_w1   = (const float*)d_in[3];
    const float* em1_b1   = (const float*)d_in[4];
    const float* em1_w2   = (const float*)d_in[5];
    const float* em1_b2   = (const float*)d_in[6];
    const float* em2_w1   = (const float*)d_in[7];
    const float* em2_b1   = (const float*)d_in[8];
    const float* em2_w2   = (const float*)d_in[9];
    const float* em2_b2   = (const float*)d_in[10];
    const float* c1_lin_w = (const float*)d_in[11];
    const float* c1_lin_b = (const float*)d_in[12];
    const float* c1_w1    = (const float*)d_in[13];
    const float* c1_b1    = (const float*)d_in[14];
    const float* c1_w2    = (const float*)d_in[15];
    const float* c1_b2    = (const float*)d_in[16];
    const float* c2_lin_w = (const float*)d_in[17];
    const float* c2_lin_b = (const float*)d_in[18];
    const float* c2_w1    = (const float*)d_in[19];
    const float* c2_b1    = (const float*)d_in[20];
    const float* c2_w2    = (const float*)d_in[21];
    const float* c2_b2    = (const float*)d_in[22];
    const float* lin1_w   = (const float*)d_in[23];
    const float* lin1_b   = (const float*)d_in[24];
    const float* lin2_w   = (const float*)d_in[25];
    const float* lin2_b   = (const float*)d_in[26];
    const float* fc_w     = (const float*)d_in[27];
    const float* fc_b     = (const float*)d_in[28];
    const int*   ei       = (const int*)d_in[29];
    const int*   batch    = (const int*)d_in[30];

    char* wsb = (char*)d_ws;
    int*   cnt  = (int*)(wsb + B_CNT);
    int*   off  = (int*)(wsb + B_OFF);
    int*   cur  = (int*)(wsb + B_CUR);
    int*   bsum = (int*)(wsb + B_BSUM);
    int2*  sedge= (int2*)(wsb + B_SEDGE);
    int*   dsta = (int*)(wsb + B_DSTA);
    float* agg  = (float*)(wsb + B_AGG);    // [N][96] for layer1, [N][192] for layer2
    float* h1   = (float*)(wsb + B_H1);
    float* h2   = (float*)(wsb + B_H2);
    float* fw   = (float*)(wsb + B_FOLD);
    unsigned short* fr  = (unsigned short*)(wsb + B_FRAG);
    unsigned short* fr2 = (unsigned short*)(wsb + B_FR2);
    float* out  = (float*)d_out;

    (void)hipMemsetAsync(d_ws, 0, ZERO_BYTES, stream);   // histogram counters only

    fold_kernel<<<(FOLD_TOTAL + 255) / 256, 256, 0, stream>>>(
        em1_w2, em1_b2, em2_w2, em2_b2, c1_lin_w, c1_lin_b, c2_lin_w, c2_lin_b,
        c1_w2, c1_b2, c2_w2, c2_b2, lin1_w, lin1_b, lin2_w, lin2_b, fw);
    fold2_kernel<<<(FOLD2_TOTAL + 255) / 256, 256, 0, stream>>>(em1_w1, em2_w1, fw, fr);
    fold3_kernel<<<(FOLD3_TOTAL + 255) / 256, 256, 0, stream>>>(c1_w1, c2_w1, fw, fr2);

    // counting sort by dst
    hist_kernel<<<N_EDGES / 256, 256, 0, stream>>>(ei, cnt);
    scan1_kernel<<<196, 256, 0, stream>>>(cnt, off, bsum);
    scan2_kernel<<<1, 256, 0, stream>>>(bsum);
    scan3_kernel<<<196, 256, 0, stream>>>(off, bsum, cur);
    scatter_kernel<<<N_EDGES / 256, 256, 0, stream>>>(ei, cur, sedge, dsta);

    // layer 1: fused edge MLP + segmented gather (q never hits HBM)
    (void)hipMemsetAsync(wsb + B_AGG, 0, (size_t)N_NODES * 96 * 4, stream);
    fused_edge_gather<6, 32><<<NCHUNKS / 4, 256, 0, stream>>>(
        edge_attr, sedge, dsta, fr + FR_W1E1, em1_b1, fr + FR_V1, fw + F_B1F, x, agg, NCHUNKS);
    mlp1_mfma_kernel<<<(NTILES + 3) / 4, 256, 0, stream>>>(x, agg, fr2, c1_b1, fw, h1);

    // layer 2
    (void)hipMemsetAsync(wsb + B_AGG, 0, (size_t)N_NODES * 192 * 4, stream);
    fused_edge_gather<12, 64><<<NCHUNKS / 4, 256, 0, stream>>>(
        edge_attr, sedge, dsta, fr + FR_W1E2, em2_b1, fr + FR_V2, fw + F_B2F, h1, agg, NCHUNKS);
    mlp2_mfma_kernel<<<(NTILES + 3) / 4, 256, 0, stream>>>(h1, agg, fr2, c2_b1, fw, h2);

    // pooling + head (fused)
    pool_kernel<<<N_GRAPHS, 256, 0, stream>>>(h2, batch, u, fc_w, fc_b, out);
}

// Round 9
// 467.904 us; speedup vs baseline: 1.0113x; 1.0113x over previous
//
#include <hip/hip_runtime.h>
#include <hip/hip_bf16.h>

#define N_NODES  50000
#define N_EDGES  800000
#define N_GRAPHS 512
#define NTILES   3125   // N_NODES / 16
#define ETILES   50000  // N_EDGES / 16
#define CT       4      // edge tiles per wave chunk
#define NCHUNKS  (ETILES / CT)   // 12500

typedef short bf16x8 __attribute__((ext_vector_type(8)));
typedef float f32x4  __attribute__((ext_vector_type(4)));

// ---------------- workspace layout (BYTE offsets, 256-aligned) ----------------
constexpr size_t B_CNT  = 0;                 // N ints (zeroed)
constexpr size_t ZERO_BYTES = 200192;
constexpr size_t B_OFF  = 200192;            // (N+1) ints
constexpr size_t B_CUR  = 400384;            // N ints
constexpr size_t B_BSUM = 600576;            // 256 ints
constexpr size_t B_SEDGE= 601600;            // E int2 (src, eid) sorted by dst — 6.4 MB
constexpr size_t B_DSTA = 7001600;           // E ints: dst of sorted edge — 3.2 MB
constexpr size_t B_FR2  = 10201600;          // mlp MFMA frags, 43008 ushorts
constexpr size_t B_AGG  = 10287616;          // N*192 f (layer2); aliased as [N][96] (layer1)
constexpr size_t B_H1   = 48687616;          // N*64 f
constexpr size_t B_H2   = 61487616;          // N*64 f
constexpr size_t B_FOLD = 74287616;          // folded weights, 43424 floats
constexpr size_t B_FRAG = 74461440;          // bf16 edge-MFMA fragment weights (22528 ushorts)
// fold-region float offsets
constexpr int F_V1H = 0;      // [64][96]   V1[t][n]
constexpr int F_B1F = 6144;   // [96]
constexpr int F_V2H = 6240;   // [64][192]  V2[t][n]
constexpr int F_B2F = 18528;  // [192]
constexpr int F_U1  = 18720;  // [3][64][64]
constexpr int F_UB1 = 31008;  // [64]
constexpr int F_U2  = 31072;  // [3][64][64]
constexpr int F_UB2 = 43360;  // [64]
constexpr int FOLD_TOTAL = 43424;
// edge frag-region ushort offsets
constexpr int FR_W1E1 = 0;      // [4][64][8]   em1_w1^T A-frags (K padded 16->32)
constexpr int FR_W1E2 = 2048;   // [4][64][8]
constexpr int FR_V1   = 4096;   // [6][2][64][8]  V1 B-frags, k-permuted
constexpr int FR_V2   = 10240;  // [12][2][64][8] V2 B-frags, k-permuted
constexpr int FOLD2_TOTAL = 22528;
// mlp frag-region (fr2) ushort offsets
constexpr int FR3_M1W = 0;      // [3][4][64][8]     c1_w1^T A-frags (K=32)
constexpr int FR3_M1U = 6144;   // [3][4][2][64][8]  U1 B-frags, k-permuted
constexpr int FR3_M2W = 18432;  // [3][4][2][64][8]  c2_w1^T A-frags (K=64)
constexpr int FR3_M2U = 30720;  // [3][4][2][64][8]  U2 B-frags, k-permuted
constexpr int FOLD3_TOTAL = 43008;

__device__ inline unsigned short bf16u(float x) {
    unsigned int ua = __float_as_uint(x);
    return (unsigned short)((ua + 0x7FFFu + ((ua >> 16) & 1u)) >> 16);
}
__device__ inline unsigned int packbf2(float a, float b) {
    unsigned int ua = __float_as_uint(a), ub = __float_as_uint(b);
    return ((ua + 0x7FFFu + ((ua >> 16) & 1u)) >> 16) |
           ((ub + 0x7FFFu + ((ub >> 16) & 1u)) & 0xFFFF0000u);
}

// ---------------- fold: precompute folded weight products (fp32) ----------------
__global__ __launch_bounds__(256) void fold_kernel(
    const float* __restrict__ em1_w2, const float* __restrict__ em1_b2,
    const float* __restrict__ em2_w2, const float* __restrict__ em2_b2,
    const float* __restrict__ c1_lin_w, const float* __restrict__ c1_lin_b,
    const float* __restrict__ c2_lin_w, const float* __restrict__ c2_lin_b,
    const float* __restrict__ c1_w2, const float* __restrict__ c1_b2,
    const float* __restrict__ c2_w2, const float* __restrict__ c2_b2,
    const float* __restrict__ lin1_w, const float* __restrict__ lin1_b,
    const float* __restrict__ lin2_w, const float* __restrict__ lin2_b,
    float* __restrict__ fw)
{
    int idx = blockIdx.x * 256 + threadIdx.x;
    if (idx >= FOLD_TOTAL) return;
    int r = idx;
    if (r < 6144) {
        int k = r / 96, c = r % 96, i = c / 32, j = c % 32;
        float s = 0.f;
        for (int m = 0; m < 64; m++) s = fmaf(em1_w2[k * 64 + m], c1_lin_w[i * 2048 + m * 32 + j], s);
        fw[F_V1H + r] = s; return;
    }
    r -= 6144;
    if (r < 96) {
        int i = r / 32, j = r % 32;
        float s = c1_lin_b[r];
        for (int m = 0; m < 64; m++) s = fmaf(em1_b2[m], c1_lin_w[i * 2048 + m * 32 + j], s);
        fw[F_B1F + r] = s; return;
    }
    r -= 96;
    if (r < 12288) {
        int k = r / 192, c = r % 192, i = c / 64, j = c % 64;
        float s = 0.f;
        for (int m = 0; m < 64; m++) s = fmaf(em2_w2[k * 64 + m], c2_lin_w[i * 4096 + m * 64 + j], s);
        fw[F_V2H + r] = s; return;
    }
    r -= 12288;
    if (r < 192) {
        int i = r / 64, j = r % 64;
        float s = c2_lin_b[r];
        for (int m = 0; m < 64; m++) s = fmaf(em2_b2[m], c2_lin_w[i * 4096 + m * 64 + j], s);
        fw[F_B2F + r] = s; return;
    }
    r -= 192;
    if (r < 12288) {
        int i = r / 4096, k = (r / 64) % 64, j = r % 64;
        float s = 0.f;
        for (int m = 0; m < 64; m++) s = fmaf(c1_w2[i * 4096 + k * 64 + m], lin1_w[(i * 64 + m) * 64 + j], s);
        fw[F_U1 + r] = s; return;
    }
    r -= 12288;
    if (r < 64) {
        float s = lin1_b[r];
        for (int i = 0; i < 3; i++)
            for (int m = 0; m < 64; m++) s = fmaf(c1_b2[i * 64 + m], lin1_w[(i * 64 + m) * 64 + r], s);
        fw[F_UB1 + r] = s; return;
    }
    r -= 64;
    if (r < 12288) {
        int i = r / 4096, k = (r / 64) % 64, j = r % 64;
        float s = 0.f;
        for (int m = 0; m < 64; m++) s = fmaf(c2_w2[i * 4096 + k * 64 + m], lin2_w[(i * 64 + m) * 64 + j], s);
        fw[F_U2 + r] = s; return;
    }
    r -= 12288;
    {
        float s = lin2_b[r];
        for (int i = 0; i < 3; i++)
            for (int m = 0; m < 64; m++) s = fmaf(c2_b2[i * 64 + m], lin2_w[(i * 64 + m) * 64 + r], s);
        fw[F_UB2 + r] = s; return;
    }
}

// ---------------- fold2: edge-MFMA bf16 fragment weights ----------------
__global__ __launch_bounds__(256) void fold2_kernel(
    const float* __restrict__ em1_w1, const float* __restrict__ em2_w1,
    const float* __restrict__ fw, unsigned short* __restrict__ fr)
{
    int idx = blockIdx.x * 256 + threadIdx.x;
    if (idx >= FOLD2_TOTAL) return;
    if (idx < 4096) {
        const float* w = (idx < 2048) ? em1_w1 : em2_w1;
        int r = idx & 2047;
        int tt = r >> 9, lane = (r >> 3) & 63, j = r & 7;
        int q = lane >> 4, k = q * 8 + j, m = tt * 16 + (lane & 15);
        fr[idx] = (k < 16) ? bf16u(w[k * 64 + m]) : (unsigned short)0;
        return;
    }
    if (idx < 10240) {
        int r = idx - 4096;
        int nt = r / 1024, ka = (r >> 9) & 1, lane = (r >> 3) & 63, j = r & 7;
        int q = lane >> 4;
        int t = 32 * ka + 16 * (j >> 2) + 4 * q + (j & 3);
        int n = nt * 16 + (lane & 15);
        fr[idx] = bf16u(fw[F_V1H + t * 96 + n]);
        return;
    }
    {
        int r = idx - 10240;
        int nt = r / 1024, ka = (r >> 9) & 1, lane = (r >> 3) & 63, j = r & 7;
        int q = lane >> 4;
        int t = 32 * ka + 16 * (j >> 2) + 4 * q + (j & 3);
        int n = nt * 16 + (lane & 15);
        fr[idx] = bf16u(fw[F_V2H + t * 192 + n]);
        return;
    }
}

// ---------------- fold3: node-MLP MFMA fragments ----------------
__global__ __launch_bounds__(256) void fold3_kernel(
    const float* __restrict__ c1_w1, const float* __restrict__ c2_w1,
    const float* __restrict__ fw, unsigned short* __restrict__ fr2)
{
    int idx = blockIdx.x * 256 + threadIdx.x;
    if (idx >= FOLD3_TOTAL) return;
    if (idx < 6144) {
        int i = idx / 2048, r = idx % 2048;
        int tt = r >> 9, lane = (r >> 3) & 63, jj = r & 7;
        int k = (lane >> 4) * 8 + jj, m = tt * 16 + (lane & 15);
        fr2[FR3_M1W + idx] = bf16u(c1_w1[i * 2048 + k * 64 + m]);
        return;
    }
    if (idx < 18432) {
        int r = idx - 6144;
        int i = r / 4096, r2 = r % 4096;
        int b = r2 >> 10, ka = (r2 >> 9) & 1, lane = (r2 >> 3) & 63, jj = r2 & 7;
        int t = 32 * ka + 16 * (jj >> 2) + 4 * (lane >> 4) + (jj & 3);
        int n = b * 16 + (lane & 15);
        fr2[FR3_M1U + r] = bf16u(fw[F_U1 + i * 4096 + t * 64 + n]);
        return;
    }
    if (idx < 30720) {
        int r = idx - 18432;
        int i = r / 4096, r2 = r % 4096;
        int tt = r2 >> 10, ka = (r2 >> 9) & 1, lane = (r2 >> 3) & 63, jj = r2 & 7;
        int k = ka * 32 + (lane >> 4) * 8 + jj, m = tt * 16 + (lane & 15);
        fr2[FR3_M2W + r] = bf16u(c2_w1[i * 4096 + k * 64 + m]);
        return;
    }
    {
        int r = idx - 30720;
        int i = r / 4096, r2 = r % 4096;
        int b = r2 >> 10, ka = (r2 >> 9) & 1, lane = (r2 >> 3) & 63, jj = r2 & 7;
        int t = 32 * ka + 16 * (jj >> 2) + 4 * (lane >> 4) + (jj & 3);
        int n = b * 16 + (lane & 15);
        fr2[FR3_M2U + r] = bf16u(fw[F_U2 + i * 4096 + t * 64 + n]);
        return;
    }
}

// ---------------- counting sort: hist -> scan -> scatter ----------------
__global__ __launch_bounds__(256) void hist_kernel(const int* __restrict__ ei, int* __restrict__ cnt) {
    int e = blockIdx.x * 256 + threadIdx.x;
    if (e < N_EDGES) atomicAdd(&cnt[ei[N_EDGES + e]], 1);
}

__global__ __launch_bounds__(256) void scan1_kernel(const int* __restrict__ cnt,
                                                    int* __restrict__ off, int* __restrict__ bsum) {
    __shared__ int sh[256];
    int t = threadIdx.x, i = blockIdx.x * 256 + t;
    int v = (i < N_NODES) ? cnt[i] : 0;
    sh[t] = v; __syncthreads();
    for (int d = 1; d < 256; d <<= 1) {
        int add = (t >= d) ? sh[t - d] : 0;
        __syncthreads();
        sh[t] += add;
        __syncthreads();
    }
    if (i < N_NODES) off[i] = sh[t] - v;
    if (t == 255) bsum[blockIdx.x] = sh[255];
}

__global__ __launch_bounds__(256) void scan2_kernel(int* __restrict__ bsum) {
    __shared__ int sh[256];
    int t = threadIdx.x;
    int v = (t < 196) ? bsum[t] : 0;
    sh[t] = v; __syncthreads();
    for (int d = 1; d < 256; d <<= 1) {
        int add = (t >= d) ? sh[t - d] : 0;
        __syncthreads();
        sh[t] += add;
        __syncthreads();
    }
    bsum[t] = sh[t] - v;
}

__global__ __launch_bounds__(256) void scan3_kernel(int* __restrict__ off, const int* __restrict__ bsum,
                                                    int* __restrict__ cur) {
    int i = blockIdx.x * 256 + threadIdx.x;
    if (i < N_NODES) {
        int o = off[i] + bsum[i >> 8];
        off[i] = o;
        cur[i] = o;
    }
    if (i == 0) off[N_NODES] = N_EDGES;
}

// scatter also records dst per sorted slot (needed by fused gather for segment bounds)
__global__ __launch_bounds__(256) void scatter_kernel(const int* __restrict__ ei, int* __restrict__ cur,
                                                      int2* __restrict__ sedge, int* __restrict__ dsta) {
    int e = blockIdx.x * 256 + threadIdx.x;
    if (e >= N_EDGES) return;
    int d = ei[N_EDGES + e];
    int p = atomicAdd(&cur[d], 1);
    sedge[p] = make_int2(ei[e], e);
    dsta[p] = d;
}

// ---------------- FUSED edge-projection MFMA + segmented gather (v8) --------
// v7 post-mortem: fp32 spill for NT=12 pushed reg pressure past the 128
// (4-waves/EU) step -> regalloc spilled to scratch (FETCH+44MB, WRITE+81MB,
// VALU 51->25%, 121us). REVERT to v6's packed-bf16 spill (VGPR 124, clean
// 137/46MB traffic) and keep setprio (NT=6 kept it in v7 and didn't regress).
// NEW: SW=97 -> 104 for the packed tile. With stride 97, quad-row term mod 32
// = 4*quad -> the 4 quads' 16-col store windows start at {0,20,8,28}: 3-way
// conflicts on 1/3 of banks (the 2.4M counter). With stride 104 (4*104%32==0)
// quads 0/2 share one window, 1/3 (XOR-16) the complement -> exactly 2
// lanes/bank everywhere = free (m136). Walk reads stay in [0,96) < 104.
#define XLOAD(i) const float xv##i = X[(size_t)__builtin_amdgcn_readlane(se.x, i) * XD + xl];
#define WSTEP(i) { \
    const int dnn = __builtin_amdgcn_readlane(dv, i); \
    if (dnn != curd) { \
        if (curd >= 0) { do_flush(!inside); inside = true; } \
        curd = dnn; \
        acc0 = acc1 = acc2 = 0.f; \
    } \
    if constexpr (PK) { \
        const int base = (i) * SW; \
        const unsigned int xr = (unsigned int)((((i) >> 2) & 1) << 4); \
        const unsigned int w0 = Lu[base + (((unsigned)lane) ^ xr)]; \
        const int i1 = (lane < 32) ? (lane + 64) : (lane - 32); \
        const unsigned int w1 = Lu[base + (((unsigned)i1) ^ xr)]; \
        const unsigned int w2 = Lu[base + (((unsigned)(lane + 32)) ^ xr)]; \
        const float q0 = __uint_as_float(w0 << 16); \
        const float q1 = (lane < 32) ? __uint_as_float(w1 << 16) \
                                     : __uint_as_float(w1 & 0xFFFF0000u); \
        const float q2 = __uint_as_float(w2 & 0xFFFF0000u); \
        const float xe = xv##i; \
        acc0 += fmaxf(xe + q0, 0.f); \
        acc1 += fmaxf(xe + q1, 0.f); \
        acc2 += fmaxf(xe + q2, 0.f); \
    } else { \
        const int base = (i) * SW; \
        const float q0 = Lf[base + lane]; \
        const float q1 = Lf[base + 64 + (lane & 31)]; \
        const float xe = xv##i; \
        acc0 += fmaxf(xe + q0, 0.f); \
        if (lane < 32) acc1 += fmaxf(xe + q1, 0.f); \
    } \
}

template<int NT, int XD>
__global__ __launch_bounds__(256, 2) void fused_edge_gather(
    const float* __restrict__ edge_attr, const int2* __restrict__ sedge,
    const int* __restrict__ dsta,
    const unsigned short* __restrict__ w1frag, const float* __restrict__ b1,
    const unsigned short* __restrict__ vfrag,  const float* __restrict__ bias2,
    const float* __restrict__ X, float* __restrict__ agg, int nChunks)
{
    constexpr int  C  = NT * 16;
    constexpr bool PK = (NT == 12);                  // packed-bf16 spill
    constexpr int  SW = PK ? 104 : (C + 2);          // words per edge row (see bank analysis)
    __shared__ unsigned int lds[4 * 16 * SW];
    const int lane = threadIdx.x & 63;
    const int wid  = threadIdx.x >> 6;
    const int col  = lane & 15;
    const int quad = lane >> 4;
    const int cw   = blockIdx.x * 4 + wid;
    if (cw >= nChunks) return;
    unsigned int* Lu = lds + wid * 16 * SW;
    float*        Lf = (float*)Lu;

    bf16x8 w1f[4];
#pragma unroll
    for (int tt = 0; tt < 4; tt++)
        w1f[tt] = *(const bf16x8*)(w1frag + (tt * 64 + lane) * 8);
    float4 b1v[4];
#pragma unroll
    for (int tt = 0; tt < 4; tt++)
        b1v[tt] = *(const float4*)(b1 + tt * 16 + quad * 4);
    float b2v[NT];
#pragma unroll
    for (int nt = 0; nt < NT; nt++) b2v[nt] = bias2[nt * 16 + col];

    const int xl = lane & (XD - 1);
    float acc0 = 0.f, acc1 = 0.f, acc2 = 0.f;
    int  curd  = -1;
    bool inside = false;

    auto do_flush = [&](bool atomicPath) {
        float* row = agg + (size_t)curd * C;
        if (!atomicPath) {
            row[lane] = acc0;
            if constexpr (PK) { row[64 + lane] = acc1; row[128 + lane] = acc2; }
            else { if (lane < 32) row[64 + lane] = acc1; }
        } else {
            atomicAdd(&row[lane], acc0);
            if constexpr (PK) { atomicAdd(&row[64 + lane], acc1); atomicAdd(&row[128 + lane], acc2); }
            else { if (lane < 32) atomicAdd(&row[64 + lane], acc1); }
        }
    };

    const int t0 = cw * CT;
    int2 se = sedge[(size_t)t0 * 16 + col];
    int  dv = dsta[(size_t)t0 * 16 + col];

    // ---- prologue: issue tile-0's scattered edge_attr raw loads ----
    float4 er0 = {0.f, 0.f, 0.f, 0.f}, er1 = {0.f, 0.f, 0.f, 0.f};
    if (quad < 2) {
        const int e0 = se.y;
        er0 = *(const float4*)(edge_attr + (size_t)e0 * 16 + quad * 8);
        er1 = *(const float4*)(edge_attr + (size_t)e0 * 16 + quad * 8 + 4);
    }

    for (int ti = 0; ti < CT; ++ti) {
        const int s = (t0 + ti) * 16 + col;

        // ---- prefetch next tile's edge metadata ----
        int2 se_n = se; int dv_n = dv;
        if (ti + 1 < CT) { se_n = sedge[s + 16]; dv_n = dsta[s + 16]; }

        // ---- 16 scattered X-row loads issued FIRST: in flight across MFMA A+B ----
        XLOAD(0)  XLOAD(1)  XLOAD(2)  XLOAD(3)
        XLOAD(4)  XLOAD(5)  XLOAD(6)  XLOAD(7)
        XLOAD(8)  XLOAD(9)  XLOAD(10) XLOAD(11)
        XLOAD(12) XLOAD(13) XLOAD(14) XLOAD(15)

        // ---- pack ea (waits only the ea loads — oldest outstanding) ----
        uint4 eau = make_uint4(0u, 0u, 0u, 0u);
        if (quad < 2) {
            eau.x = packbf2(er0.x, er0.y); eau.y = packbf2(er0.z, er0.w);
            eau.z = packbf2(er1.x, er1.y); eau.w = packbf2(er1.z, er1.w);
        }
        const bf16x8 eaf = __builtin_bit_cast(bf16x8, eau);

        // ---- edge MLP layer A ----
        __builtin_amdgcn_s_setprio(1);
        f32x4 c1[4];
#pragma unroll
        for (int tt = 0; tt < 4; tt++) {
            f32x4 ci = {b1v[tt].x, b1v[tt].y, b1v[tt].z, b1v[tt].w};
            c1[tt] = __builtin_amdgcn_mfma_f32_16x16x32_bf16(w1f[tt], eaf, ci, 0, 0, 0);
        }
        __builtin_amdgcn_s_setprio(0);
        bf16x8 a2[2];
#pragma unroll
        for (int ka = 0; ka < 2; ka++) {
            uint4 au;
            au.x = packbf2(fmaxf(c1[2 * ka][0], 0.f),     fmaxf(c1[2 * ka][1], 0.f));
            au.y = packbf2(fmaxf(c1[2 * ka][2], 0.f),     fmaxf(c1[2 * ka][3], 0.f));
            au.z = packbf2(fmaxf(c1[2 * ka + 1][0], 0.f), fmaxf(c1[2 * ka + 1][1], 0.f));
            au.w = packbf2(fmaxf(c1[2 * ka + 1][2], 0.f), fmaxf(c1[2 * ka + 1][3], 0.f));
            a2[ka] = __builtin_bit_cast(bf16x8, au);
        }

        // ---- edge MLP layer B, V-frags streamed; spill to LDS ----
        __builtin_amdgcn_s_setprio(1);
        if constexpr (PK) {
            const unsigned int xr = (unsigned int)((quad & 1) << 4);
#pragma unroll
            for (int nt = 0; nt < 6; nt++) {
                const bf16x8 va0 = *(const bf16x8*)(vfrag + ((nt * 2 + 0) * 64 + lane) * 8);
                const bf16x8 va1 = *(const bf16x8*)(vfrag + ((nt * 2 + 1) * 64 + lane) * 8);
                f32x4 ca = {b2v[nt], b2v[nt], b2v[nt], b2v[nt]};
                ca = __builtin_amdgcn_mfma_f32_16x16x32_bf16(a2[0], va0, ca, 0, 0, 0);
                ca = __builtin_amdgcn_mfma_f32_16x16x32_bf16(a2[1], va1, ca, 0, 0, 0);
                const bf16x8 vb0 = *(const bf16x8*)(vfrag + (((nt + 6) * 2 + 0) * 64 + lane) * 8);
                const bf16x8 vb1 = *(const bf16x8*)(vfrag + (((nt + 6) * 2 + 1) * 64 + lane) * 8);
                f32x4 cb = {b2v[nt + 6], b2v[nt + 6], b2v[nt + 6], b2v[nt + 6]};
                cb = __builtin_amdgcn_mfma_f32_16x16x32_bf16(a2[0], vb0, cb, 0, 0, 0);
                cb = __builtin_amdgcn_mfma_f32_16x16x32_bf16(a2[1], vb1, cb, 0, 0, 0);
#pragma unroll
                for (int r = 0; r < 4; r++)
                    Lu[(quad * 4 + r) * SW + (((unsigned)(nt * 16 + col)) ^ xr)] =
                        packbf2(ca[r], cb[r]);
            }
        } else {
#pragma unroll
            for (int nt = 0; nt < NT; nt++) {
                const bf16x8 v0 = *(const bf16x8*)(vfrag + ((nt * 2 + 0) * 64 + lane) * 8);
                const bf16x8 v1 = *(const bf16x8*)(vfrag + ((nt * 2 + 1) * 64 + lane) * 8);
                f32x4 c = {b2v[nt], b2v[nt], b2v[nt], b2v[nt]};
                c = __builtin_amdgcn_mfma_f32_16x16x32_bf16(a2[0], v0, c, 0, 0, 0);
                c = __builtin_amdgcn_mfma_f32_16x16x32_bf16(a2[1], v1, c, 0, 0, 0);
#pragma unroll
                for (int r = 0; r < 4; r++)
                    Lf[(quad * 4 + r) * SW + nt * 16 + col] = c[r];
            }
        }
        __builtin_amdgcn_s_setprio(0);

        // ---- issue NEXT tile's edge_attr raw loads: covered by the walk ----
        if (ti + 1 < CT && quad < 2) {
            const int en = se_n.y;
            er0 = *(const float4*)(edge_attr + (size_t)en * 16 + quad * 8);
            er1 = *(const float4*)(edge_attr + (size_t)en * 16 + quad * 8 + 4);
        }

        // ---- segmented walk: LDS + VALU; dst via readlane (SALU) ----
        WSTEP(0)  WSTEP(1)  WSTEP(2)  WSTEP(3)
        WSTEP(4)  WSTEP(5)  WSTEP(6)  WSTEP(7)
        WSTEP(8)  WSTEP(9)  WSTEP(10) WSTEP(11)
        WSTEP(12) WSTEP(13) WSTEP(14) WSTEP(15)

        se = se_n; dv = dv_n;
    }
    do_flush(true);   // final open segment may continue into the next chunk
}
#undef XLOAD
#undef WSTEP

// ---------------- node MLP layer 1 via MFMA (16 nodes per wave) ----------------
__global__ __launch_bounds__(256) void mlp1_mfma_kernel(
    const float* __restrict__ x, const float* __restrict__ agg1,
    const unsigned short* __restrict__ fr2, const float* __restrict__ c1_b1,
    const float* __restrict__ fw, float* __restrict__ h1)
{
    const int lane = threadIdx.x & 63, wid = threadIdx.x >> 6;
    const int tile = blockIdx.x * 4 + wid;
    if (tile >= NTILES) return;
    const int col = lane & 15, quad = lane >> 4;
    const int node = tile * 16 + col;

    const float4 xa = *(const float4*)(x + (size_t)node * 32 + quad * 8);
    const float4 xb = *(const float4*)(x + (size_t)node * 32 + quad * 8 + 4);

    f32x4 c2[4];
#pragma unroll
    for (int b = 0; b < 4; b++) {
        const float ub = fw[F_UB1 + b * 16 + col];
        c2[b] = {ub, ub, ub, ub};
    }
#pragma unroll
    for (int i = 0; i < 3; i++) {
        const float4 a0 = *(const float4*)(agg1 + (size_t)node * 96 + i * 32 + quad * 8);
        const float4 a1 = *(const float4*)(agg1 + (size_t)node * 96 + i * 32 + quad * 8 + 4);
        uint4 iu;
        iu.x = packbf2(xa.x + a0.x, xa.y + a0.y);
        iu.y = packbf2(xa.z + a0.z, xa.w + a0.w);
        iu.z = packbf2(xb.x + a1.x, xb.y + a1.y);
        iu.w = packbf2(xb.z + a1.z, xb.w + a1.w);
        const bf16x8 inf = __builtin_bit_cast(bf16x8, iu);

        f32x4 c1[4];
#pragma unroll
        for (int tt = 0; tt < 4; tt++) {
            const bf16x8 wf = *(const bf16x8*)(fr2 + FR3_M1W + ((i * 4 + tt) * 64 + lane) * 8);
            const float4 bi = *(const float4*)(c1_b1 + i * 64 + tt * 16 + quad * 4);
            f32x4 ci = {bi.x, bi.y, bi.z, bi.w};
            c1[tt] = __builtin_amdgcn_mfma_f32_16x16x32_bf16(wf, inf, ci, 0, 0, 0);
        }
        bf16x8 a2[2];
#pragma unroll
        for (int ka = 0; ka < 2; ka++) {
            uint4 au;
            au.x = packbf2(fmaxf(c1[2 * ka][0], 0.f),     fmaxf(c1[2 * ka][1], 0.f));
            au.y = packbf2(fmaxf(c1[2 * ka][2], 0.f),     fmaxf(c1[2 * ka][3], 0.f));
            au.z = packbf2(fmaxf(c1[2 * ka + 1][0], 0.f), fmaxf(c1[2 * ka + 1][1], 0.f));
            au.w = packbf2(fmaxf(c1[2 * ka + 1][2], 0.f), fmaxf(c1[2 * ka + 1][3], 0.f));
            a2[ka] = __builtin_bit_cast(bf16x8, au);
        }
#pragma unroll
        for (int b = 0; b < 4; b++)
#pragma unroll
            for (int ka = 0; ka < 2; ka++) {
                const bf16x8 uf = *(const bf16x8*)(fr2 + FR3_M1U + (((i * 4 + b) * 2 + ka) * 64 + lane) * 8);
                c2[b] = __builtin_amdgcn_mfma_f32_16x16x32_bf16(a2[ka], uf, c2[b], 0, 0, 0);
            }
    }
    const int rowb = tile * 16 + quad * 4;
#pragma unroll
    for (int b = 0; b < 4; b++)
#pragma unroll
        for (int r = 0; r < 4; r++)
            h1[(size_t)(rowb + r) * 64 + b * 16 + col] = fmaxf(c2[b][r], 0.f);
}

// ---------------- node MLP layer 2 via MFMA (16 nodes per wave) ----------------
__global__ __launch_bounds__(256) void mlp2_mfma_kernel(
    const float* __restrict__ h1, const float* __restrict__ agg2,
    const unsigned short* __restrict__ fr2, const float* __restrict__ c2_b1,
    const float* __restrict__ fw, float* __restrict__ h2)
{
    const int lane = threadIdx.x & 63, wid = threadIdx.x >> 6;
    const int tile = blockIdx.x * 4 + wid;
    if (tile >= NTILES) return;
    const int col = lane & 15, quad = lane >> 4;
    const int node = tile * 16 + col;

    float4 hv[4];
#pragma unroll
    for (int p = 0; p < 4; p++)
        hv[p] = *(const float4*)(h1 + (size_t)node * 64 + (p >> 1) * 32 + quad * 8 + (p & 1) * 4);

    f32x4 c2[4];
#pragma unroll
    for (int b = 0; b < 4; b++) {
        const float ub = fw[F_UB2 + b * 16 + col];
        c2[b] = {ub, ub, ub, ub};
    }
#pragma unroll
    for (int i = 0; i < 3; i++) {
        bf16x8 inf[2];
#pragma unroll
        for (int ka = 0; ka < 2; ka++) {
            const float4 a0 = *(const float4*)(agg2 + (size_t)node * 192 + i * 64 + ka * 32 + quad * 8);
            const float4 a1 = *(const float4*)(agg2 + (size_t)node * 192 + i * 64 + ka * 32 + quad * 8 + 4);
            const float4 h0 = hv[ka * 2], h1v = hv[ka * 2 + 1];
            uint4 iu;
            iu.x = packbf2(h0.x + a0.x, h0.y + a0.y);
            iu.y = packbf2(h0.z + a0.z, h0.w + a0.w);
            iu.z = packbf2(h1v.x + a1.x, h1v.y + a1.y);
            iu.w = packbf2(h1v.z + a1.z, h1v.w + a1.w);
            inf[ka] = __builtin_bit_cast(bf16x8, iu);
        }
        f32x4 c1[4];
#pragma unroll
        for (int tt = 0; tt < 4; tt++) {
            const bf16x8 wf0 = *(const bf16x8*)(fr2 + FR3_M2W + (((i * 4 + tt) * 2 + 0) * 64 + lane) * 8);
            const bf16x8 wf1 = *(const bf16x8*)(fr2 + FR3_M2W + (((i * 4 + tt) * 2 + 1) * 64 + lane) * 8);
            const float4 bi = *(const float4*)(c2_b1 + i * 64 + tt * 16 + quad * 4);
            f32x4 ci = {bi.x, bi.y, bi.z, bi.w};
            ci = __builtin_amdgcn_mfma_f32_16x16x32_bf16(wf0, inf[0], ci, 0, 0, 0);
            c1[tt] = __builtin_amdgcn_mfma_f32_16x16x32_bf16(wf1, inf[1], ci, 0, 0, 0);
        }
        bf16x8 a2[2];
#pragma unroll
        for (int ka = 0; ka < 2; ka++) {
            uint4 au;
            au.x = packbf2(fmaxf(c1[2 * ka][0], 0.f),     fmaxf(c1[2 * ka][1], 0.f));
            au.y = packbf2(fmaxf(c1[2 * ka][2], 0.f),     fmaxf(c1[2 * ka][3], 0.f));
            au.z = packbf2(fmaxf(c1[2 * ka + 1][0], 0.f), fmaxf(c1[2 * ka + 1][1], 0.f));
            au.w = packbf2(fmaxf(c1[2 * ka + 1][2], 0.f), fmaxf(c1[2 * ka + 1][3], 0.f));
            a2[ka] = __builtin_bit_cast(bf16x8, au);
        }
#pragma unroll
        for (int b = 0; b < 4; b++)
#pragma unroll
            for (int ka = 0; ka < 2; ka++) {
                const bf16x8 uf = *(const bf16x8*)(fr2 + FR3_M2U + (((i * 4 + b) * 2 + ka) * 64 + lane) * 8);
                c2[b] = __builtin_amdgcn_mfma_f32_16x16x32_bf16(a2[ka], uf, c2[b], 0, 0, 0);
            }
    }
    const int rowb = tile * 16 + quad * 4;
#pragma unroll
    for (int b = 0; b < 4; b++)
#pragma unroll
        for (int r = 0; r < 4; r++)
            h2[(size_t)(rowb + r) * 64 + b * 16 + col] = fmaxf(c2[b][r], 0.f);
}

// ---------------- pooling + head (fused; batch is sorted) ----------------
__global__ __launch_bounds__(256) void pool_kernel(
    const float* __restrict__ h2, const int* __restrict__ batch,
    const float* __restrict__ u, const float* __restrict__ fc_w,
    const float* __restrict__ fc_b, float* __restrict__ out)
{
    __shared__ float red[256];
    const int g = blockIdx.x, t = threadIdx.x;
    int lo = 0, hi = N_NODES;
    while (lo < hi) { int m = (lo + hi) >> 1; if (batch[m] < g) lo = m + 1; else hi = m; }
    int lo2 = lo, hi2 = N_NODES;
    while (lo2 < hi2) { int m = (lo2 + hi2) >> 1; if (batch[m] < g + 1) lo2 = m + 1; else hi2 = m; }

    const int col = t & 63, ch = t >> 6;
    float s = 0.f;
    for (int idx = lo + ch; idx < lo2; idx += 4) s += h2[(size_t)idx * 64 + col];
    red[t] = s;
    __syncthreads();
    if (t < 64) red[t] = red[t] + red[64 + t] + red[128 + t] + red[192 + t];
    __syncthreads();
    if (t == 0) {
        const float inv = 1.f / fmaxf((float)(lo2 - lo), 1.f);
        float sv = fc_b[0];
        for (int j = 0; j < 64; j++) sv = fmaf(red[j] * inv, fc_w[j], sv);
        for (int k = 0; k < 32; k++) sv = fmaf(u[(size_t)g * 32 + k], fc_w[64 + k], sv);
        out[g] = sv;
    }
}

extern "C" void kernel_launch(void* const* d_in, const int* in_sizes, int n_in,
                              void* d_out, int out_size, void* d_ws, size_t ws_size,
                              hipStream_t stream) {
    (void)in_sizes; (void)n_in; (void)out_size; (void)ws_size;
    const float* x        = (const float*)d_in[0];
    const float* edge_attr= (const float*)d_in[1];
    const float* u        = (const float*)d_in[2];
    const float* em1_w1   = (const float*)d_in[3];
    const float* em1_b1   = (const float*)d_in[4];
    const float* em1_w2   = (const float*)d_in[5];
    const float* em1_b2   = (const float*)d_in[6];
    const float* em2_w1   = (const float*)d_in[7];
    const float* em2_b1   = (const float*)d_in[8];
    const float* em2_w2   = (const float*)d_in[9];
    const float* em2_b2   = (const float*)d_in[10];
    const float* c1_lin_w = (const float*)d_in[11];
    const float* c1_lin_b = (const float*)d_in[12];
    const float* c1_w1    = (const float*)d_in[13];
    const float* c1_b1    = (const float*)d_in[14];
    const float* c1_w2    = (const float*)d_in[15];
    const float* c1_b2    = (const float*)d_in[16];
    const float* c2_lin_w = (const float*)d_in[17];
    const float* c2_lin_b = (const float*)d_in[18];
    const float* c2_w1    = (const float*)d_in[19];
    const float* c2_b1    = (const float*)d_in[20];
    const float* c2_w2    = (const float*)d_in[21];
    const float* c2_b2    = (const float*)d_in[22];
    const float* lin1_w   = (const float*)d_in[23];
    const float* lin1_b   = (const float*)d_in[24];
    const float* lin2_w   = (const float*)d_in[25];
    const float* lin2_b   = (const float*)d_in[26];
    const float* fc_w     = (const float*)d_in[27];
    const float* fc_b     = (const float*)d_in[28];
    const int*   ei       = (const int*)d_in[29];
    const int*   batch    = (const int*)d_in[30];

    char* wsb = (char*)d_ws;
    int*   cnt  = (int*)(wsb + B_CNT);
    int*   off  = (int*)(wsb + B_OFF);
    int*   cur  = (int*)(wsb + B_CUR);
    int*   bsum = (int*)(wsb + B_BSUM);
    int2*  sedge= (int2*)(wsb + B_SEDGE);
    int*   dsta = (int*)(wsb + B_DSTA);
    float* agg  = (float*)(wsb + B_AGG);    // [N][96] for layer1, [N][192] for layer2
    float* h1   = (float*)(wsb + B_H1);
    float* h2   = (float*)(wsb + B_H2);
    float* fw   = (float*)(wsb + B_FOLD);
    unsigned short* fr  = (unsigned short*)(wsb + B_FRAG);
    unsigned short* fr2 = (unsigned short*)(wsb + B_FR2);
    float* out  = (float*)d_out;

    (void)hipMemsetAsync(d_ws, 0, ZERO_BYTES, stream);   // histogram counters only

    fold_kernel<<<(FOLD_TOTAL + 255) / 256, 256, 0, stream>>>(
        em1_w2, em1_b2, em2_w2, em2_b2, c1_lin_w, c1_lin_b, c2_lin_w, c2_lin_b,
        c1_w2, c1_b2, c2_w2, c2_b2, lin1_w, lin1_b, lin2_w, lin2_b, fw);
    fold2_kernel<<<(FOLD2_TOTAL + 255) / 256, 256, 0, stream>>>(em1_w1, em2_w1, fw, fr);
    fold3_kernel<<<(FOLD3_TOTAL + 255) / 256, 256, 0, stream>>>(c1_w1, c2_w1, fw, fr2);

    // counting sort by dst
    hist_kernel<<<N_EDGES / 256, 256, 0, stream>>>(ei, cnt);
    scan1_kernel<<<196, 256, 0, stream>>>(cnt, off, bsum);
    scan2_kernel<<<1, 256, 0, stream>>>(bsum);
    scan3_kernel<<<196, 256, 0, stream>>>(off, bsum, cur);
    scatter_kernel<<<N_EDGES / 256, 256, 0, stream>>>(ei, cur, sedge, dsta);

    // layer 1: fused edge MLP + segmented gather (q never hits HBM)
    (void)hipMemsetAsync(wsb + B_AGG, 0, (size_t)N_NODES * 96 * 4, stream);
    fused_edge_gather<6, 32><<<NCHUNKS / 4, 256, 0, stream>>>(
        edge_attr, sedge, dsta, fr + FR_W1E1, em1_b1, fr + FR_V1, fw + F_B1F, x, agg, NCHUNKS);
    mlp1_mfma_kernel<<<(NTILES + 3) / 4, 256, 0, stream>>>(x, agg, fr2, c1_b1, fw, h1);

    // layer 2
    (void)hipMemsetAsync(wsb + B_AGG, 0, (size_t)N_NODES * 192 * 4, stream);
    fused_edge_gather<12, 64><<<NCHUNKS / 4, 256, 0, stream>>>(
        edge_attr, sedge, dsta, fr + FR_W1E2, em2_b1, fr + FR_V2, fw + F_B2F, h1, agg, NCHUNKS);
    mlp2_mfma_kernel<<<(NTILES + 3) / 4, 256, 0, stream>>>(h1, agg, fr2, c2_b1, fw, h2);

    // pooling + head (fused)
    pool_kernel<<<N_GRAPHS, 256, 0, stream>>>(h2, batch, u, fc_w, fc_b, out);
}

// Round 10
// 454.783 us; speedup vs baseline: 1.0405x; 1.0289x over previous
//
#include <hip/hip_runtime.h>
#include <hip/hip_bf16.h>

#define N_NODES  50000
#define N_EDGES  800000
#define N_GRAPHS 512
#define NTILES   3125   // N_NODES / 16
#define ETILES   50000  // N_EDGES / 16
#define CT       4      // edge tiles per wave chunk
#define NCHUNKS  (ETILES / CT)   // 12500

typedef short bf16x8 __attribute__((ext_vector_type(8)));
typedef float f32x4  __attribute__((ext_vector_type(4)));

// ---------------- workspace layout (BYTE offsets, 256-aligned) ----------------
constexpr size_t B_CNT  = 0;                 // N ints (zeroed)
constexpr size_t ZERO_BYTES = 200192;
constexpr size_t B_OFF  = 200192;            // (N+1) ints
constexpr size_t B_CUR  = 400384;            // N ints
constexpr size_t B_BSUM = 600576;            // 256 ints
constexpr size_t B_SEDGE= 601600;            // E int2 (src, eid) sorted by dst — 6.4 MB
constexpr size_t B_DSTA = 7001600;           // E ints: dst of sorted edge — 3.2 MB
constexpr size_t B_FR2  = 10201600;          // mlp MFMA frags, 43008 ushorts
constexpr size_t B_AGG  = 10287616;          // N*192 f (layer2); aliased as [N][96] (layer1)
constexpr size_t B_H1   = 48687616;          // N*64 f
constexpr size_t B_H2   = 61487616;          // N*64 f
constexpr size_t B_FOLD = 74287616;          // folded weights, 43424 floats
constexpr size_t B_FRAG = 74461440;          // bf16 edge-MFMA fragment weights (22528 ushorts)
// fold-region float offsets
constexpr int F_V1H = 0;      // [64][96]   V1[t][n]
constexpr int F_B1F = 6144;   // [96]
constexpr int F_V2H = 6240;   // [64][192]  V2[t][n]
constexpr int F_B2F = 18528;  // [192]
constexpr int F_U1  = 18720;  // [3][64][64]
constexpr int F_UB1 = 31008;  // [64]
constexpr int F_U2  = 31072;  // [3][64][64]
constexpr int F_UB2 = 43360;  // [64]
constexpr int FOLD_TOTAL = 43424;
// edge frag-region ushort offsets
constexpr int FR_W1E1 = 0;      // [4][64][8]   em1_w1^T A-frags (K padded 16->32)
constexpr int FR_W1E2 = 2048;   // [4][64][8]
constexpr int FR_V1   = 4096;   // [6][2][64][8]  V1 B-frags, k-permuted
constexpr int FR_V2   = 10240;  // [12][2][64][8] V2 B-frags, k-permuted
constexpr int FOLD2_TOTAL = 22528;
// mlp frag-region (fr2) ushort offsets
constexpr int FR3_M1W = 0;      // [3][4][64][8]     c1_w1^T A-frags (K=32)
constexpr int FR3_M1U = 6144;   // [3][4][2][64][8]  U1 B-frags, k-permuted
constexpr int FR3_M2W = 18432;  // [3][4][2][64][8]  c2_w1^T A-frags (K=64)
constexpr int FR3_M2U = 30720;  // [3][4][2][64][8]  U2 B-frags, k-permuted
constexpr int FOLD3_TOTAL = 43008;

__device__ inline unsigned short bf16u(float x) {
    unsigned int ua = __float_as_uint(x);
    return (unsigned short)((ua + 0x7FFFu + ((ua >> 16) & 1u)) >> 16);
}
__device__ inline unsigned int packbf2(float a, float b) {
    unsigned int ua = __float_as_uint(a), ub = __float_as_uint(b);
    return ((ua + 0x7FFFu + ((ua >> 16) & 1u)) >> 16) |
           ((ub + 0x7FFFu + ((ub >> 16) & 1u)) & 0xFFFF0000u);
}

// ---------------- fold: precompute folded weight products (fp32) ----------------
__global__ __launch_bounds__(256) void fold_kernel(
    const float* __restrict__ em1_w2, const float* __restrict__ em1_b2,
    const float* __restrict__ em2_w2, const float* __restrict__ em2_b2,
    const float* __restrict__ c1_lin_w, const float* __restrict__ c1_lin_b,
    const float* __restrict__ c2_lin_w, const float* __restrict__ c2_lin_b,
    const float* __restrict__ c1_w2, const float* __restrict__ c1_b2,
    const float* __restrict__ c2_w2, const float* __restrict__ c2_b2,
    const float* __restrict__ lin1_w, const float* __restrict__ lin1_b,
    const float* __restrict__ lin2_w, const float* __restrict__ lin2_b,
    float* __restrict__ fw)
{
    int idx = blockIdx.x * 256 + threadIdx.x;
    if (idx >= FOLD_TOTAL) return;
    int r = idx;
    if (r < 6144) {
        int k = r / 96, c = r % 96, i = c / 32, j = c % 32;
        float s = 0.f;
        for (int m = 0; m < 64; m++) s = fmaf(em1_w2[k * 64 + m], c1_lin_w[i * 2048 + m * 32 + j], s);
        fw[F_V1H + r] = s; return;
    }
    r -= 6144;
    if (r < 96) {
        int i = r / 32, j = r % 32;
        float s = c1_lin_b[r];
        for (int m = 0; m < 64; m++) s = fmaf(em1_b2[m], c1_lin_w[i * 2048 + m * 32 + j], s);
        fw[F_B1F + r] = s; return;
    }
    r -= 96;
    if (r < 12288) {
        int k = r / 192, c = r % 192, i = c / 64, j = c % 64;
        float s = 0.f;
        for (int m = 0; m < 64; m++) s = fmaf(em2_w2[k * 64 + m], c2_lin_w[i * 4096 + m * 64 + j], s);
        fw[F_V2H + r] = s; return;
    }
    r -= 12288;
    if (r < 192) {
        int i = r / 64, j = r % 64;
        float s = c2_lin_b[r];
        for (int m = 0; m < 64; m++) s = fmaf(em2_b2[m], c2_lin_w[i * 4096 + m * 64 + j], s);
        fw[F_B2F + r] = s; return;
    }
    r -= 192;
    if (r < 12288) {
        int i = r / 4096, k = (r / 64) % 64, j = r % 64;
        float s = 0.f;
        for (int m = 0; m < 64; m++) s = fmaf(c1_w2[i * 4096 + k * 64 + m], lin1_w[(i * 64 + m) * 64 + j], s);
        fw[F_U1 + r] = s; return;
    }
    r -= 12288;
    if (r < 64) {
        float s = lin1_b[r];
        for (int i = 0; i < 3; i++)
            for (int m = 0; m < 64; m++) s = fmaf(c1_b2[i * 64 + m], lin1_w[(i * 64 + m) * 64 + r], s);
        fw[F_UB1 + r] = s; return;
    }
    r -= 64;
    if (r < 12288) {
        int i = r / 4096, k = (r / 64) % 64, j = r % 64;
        float s = 0.f;
        for (int m = 0; m < 64; m++) s = fmaf(c2_w2[i * 4096 + k * 64 + m], lin2_w[(i * 64 + m) * 64 + j], s);
        fw[F_U2 + r] = s; return;
    }
    r -= 12288;
    {
        float s = lin2_b[r];
        for (int i = 0; i < 3; i++)
            for (int m = 0; m < 64; m++) s = fmaf(c2_b2[i * 64 + m], lin2_w[(i * 64 + m) * 64 + r], s);
        fw[F_UB2 + r] = s; return;
    }
}

// ---------------- fold2: edge-MFMA bf16 fragment weights ----------------
__global__ __launch_bounds__(256) void fold2_kernel(
    const float* __restrict__ em1_w1, const float* __restrict__ em2_w1,
    const float* __restrict__ fw, unsigned short* __restrict__ fr)
{
    int idx = blockIdx.x * 256 + threadIdx.x;
    if (idx >= FOLD2_TOTAL) return;
    if (idx < 4096) {
        const float* w = (idx < 2048) ? em1_w1 : em2_w1;
        int r = idx & 2047;
        int tt = r >> 9, lane = (r >> 3) & 63, j = r & 7;
        int q = lane >> 4, k = q * 8 + j, m = tt * 16 + (lane & 15);
        fr[idx] = (k < 16) ? bf16u(w[k * 64 + m]) : (unsigned short)0;
        return;
    }
    if (idx < 10240) {
        int r = idx - 4096;
        int nt = r / 1024, ka = (r >> 9) & 1, lane = (r >> 3) & 63, j = r & 7;
        int q = lane >> 4;
        int t = 32 * ka + 16 * (j >> 2) + 4 * q + (j & 3);
        int n = nt * 16 + (lane & 15);
        fr[idx] = bf16u(fw[F_V1H + t * 96 + n]);
        return;
    }
    {
        int r = idx - 10240;
        int nt = r / 1024, ka = (r >> 9) & 1, lane = (r >> 3) & 63, j = r & 7;
        int q = lane >> 4;
        int t = 32 * ka + 16 * (j >> 2) + 4 * q + (j & 3);
        int n = nt * 16 + (lane & 15);
        fr[idx] = bf16u(fw[F_V2H + t * 192 + n]);
        return;
    }
}

// ---------------- fold3: node-MLP MFMA fragments ----------------
__global__ __launch_bounds__(256) void fold3_kernel(
    const float* __restrict__ c1_w1, const float* __restrict__ c2_w1,
    const float* __restrict__ fw, unsigned short* __restrict__ fr2)
{
    int idx = blockIdx.x * 256 + threadIdx.x;
    if (idx >= FOLD3_TOTAL) return;
    if (idx < 6144) {
        int i = idx / 2048, r = idx % 2048;
        int tt = r >> 9, lane = (r >> 3) & 63, jj = r & 7;
        int k = (lane >> 4) * 8 + jj, m = tt * 16 + (lane & 15);
        fr2[FR3_M1W + idx] = bf16u(c1_w1[i * 2048 + k * 64 + m]);
        return;
    }
    if (idx < 18432) {
        int r = idx - 6144;
        int i = r / 4096, r2 = r % 4096;
        int b = r2 >> 10, ka = (r2 >> 9) & 1, lane = (r2 >> 3) & 63, jj = r2 & 7;
        int t = 32 * ka + 16 * (jj >> 2) + 4 * (lane >> 4) + (jj & 3);
        int n = b * 16 + (lane & 15);
        fr2[FR3_M1U + r] = bf16u(fw[F_U1 + i * 4096 + t * 64 + n]);
        return;
    }
    if (idx < 30720) {
        int r = idx - 18432;
        int i = r / 4096, r2 = r % 4096;
        int tt = r2 >> 10, ka = (r2 >> 9) & 1, lane = (r2 >> 3) & 63, jj = r2 & 7;
        int k = ka * 32 + (lane >> 4) * 8 + jj, m = tt * 16 + (lane & 15);
        fr2[FR3_M2W + r] = bf16u(c2_w1[i * 4096 + k * 64 + m]);
        return;
    }
    {
        int r = idx - 30720;
        int i = r / 4096, r2 = r % 4096;
        int b = r2 >> 10, ka = (r2 >> 9) & 1, lane = (r2 >> 3) & 63, jj = r2 & 7;
        int t = 32 * ka + 16 * (jj >> 2) + 4 * (lane >> 4) + (jj & 3);
        int n = b * 16 + (lane & 15);
        fr2[FR3_M2U + r] = bf16u(fw[F_U2 + i * 4096 + t * 64 + n]);
        return;
    }
}

// ---------------- counting sort: hist -> scan -> scatter ----------------
__global__ __launch_bounds__(256) void hist_kernel(const int* __restrict__ ei, int* __restrict__ cnt) {
    int e = blockIdx.x * 256 + threadIdx.x;
    if (e < N_EDGES) atomicAdd(&cnt[ei[N_EDGES + e]], 1);
}

__global__ __launch_bounds__(256) void scan1_kernel(const int* __restrict__ cnt,
                                                    int* __restrict__ off, int* __restrict__ bsum) {
    __shared__ int sh[256];
    int t = threadIdx.x, i = blockIdx.x * 256 + t;
    int v = (i < N_NODES) ? cnt[i] : 0;
    sh[t] = v; __syncthreads();
    for (int d = 1; d < 256; d <<= 1) {
        int add = (t >= d) ? sh[t - d] : 0;
        __syncthreads();
        sh[t] += add;
        __syncthreads();
    }
    if (i < N_NODES) off[i] = sh[t] - v;
    if (t == 255) bsum[blockIdx.x] = sh[255];
}

__global__ __launch_bounds__(256) void scan2_kernel(int* __restrict__ bsum) {
    __shared__ int sh[256];
    int t = threadIdx.x;
    int v = (t < 196) ? bsum[t] : 0;
    sh[t] = v; __syncthreads();
    for (int d = 1; d < 256; d <<= 1) {
        int add = (t >= d) ? sh[t - d] : 0;
        __syncthreads();
        sh[t] += add;
        __syncthreads();
    }
    bsum[t] = sh[t] - v;
}

__global__ __launch_bounds__(256) void scan3_kernel(int* __restrict__ off, const int* __restrict__ bsum,
                                                    int* __restrict__ cur) {
    int i = blockIdx.x * 256 + threadIdx.x;
    if (i < N_NODES) {
        int o = off[i] + bsum[i >> 8];
        off[i] = o;
        cur[i] = o;
    }
    if (i == 0) off[N_NODES] = N_EDGES;
}

// scatter also records dst per sorted slot (needed by fused gather for segment bounds)
__global__ __launch_bounds__(256) void scatter_kernel(const int* __restrict__ ei, int* __restrict__ cur,
                                                      int2* __restrict__ sedge, int* __restrict__ dsta) {
    int e = blockIdx.x * 256 + threadIdx.x;
    if (e >= N_EDGES) return;
    int d = ei[N_EDGES + e];
    int p = atomicAdd(&cur[d], 1);
    sedge[p] = make_int2(ei[e], e);
    dsta[p] = d;
}

// ---------------- FUSED edge-projection MFMA + segmented gather (v9) --------
// v8 post-mortem: bank-conflict fix verified (2.4M->0) but time unchanged ->
// conflicts weren't critical-path. Counters: HBM 25%, VALU 51%, occ 19%
// (~2 blocks/CU) -> latency-bound, too few waves. The 4 waves per 256-thread
// block are fully INDEPENDENT (own chunk, own LDS slice, no syncthreads) —
// the grouping is cosmetic and quantizes residency in 4-wave lumps against
// the unified VGPR+AGPR budget. v9: 64-thread workgroups (1 wave/block),
// grid=NCHUNKS. LDS/block ~6.7KB (24 blocks/CU by LDS); dispatcher places
// waves individually -> more co-resident waves to hide walk/gather latency.
// launch_bounds(64,2) keeps the relaxed VGPR cap that gave the clean 124-VGPR
// allocation. Kill-tells unchanged (VGPR drop + traffic explosion = spill).
#define XLOAD(i) const float xv##i = X[(size_t)__builtin_amdgcn_readlane(se.x, i) * XD + xl];
#define WSTEP(i) { \
    const int dnn = __builtin_amdgcn_readlane(dv, i); \
    if (dnn != curd) { \
        if (curd >= 0) { do_flush(!inside); inside = true; } \
        curd = dnn; \
        acc0 = acc1 = acc2 = 0.f; \
    } \
    if constexpr (PK) { \
        const int base = (i) * SW; \
        const unsigned int xr = (unsigned int)((((i) >> 2) & 1) << 4); \
        const unsigned int w0 = Lu[base + (((unsigned)lane) ^ xr)]; \
        const int i1 = (lane < 32) ? (lane + 64) : (lane - 32); \
        const unsigned int w1 = Lu[base + (((unsigned)i1) ^ xr)]; \
        const unsigned int w2 = Lu[base + (((unsigned)(lane + 32)) ^ xr)]; \
        const float q0 = __uint_as_float(w0 << 16); \
        const float q1 = (lane < 32) ? __uint_as_float(w1 << 16) \
                                     : __uint_as_float(w1 & 0xFFFF0000u); \
        const float q2 = __uint_as_float(w2 & 0xFFFF0000u); \
        const float xe = xv##i; \
        acc0 += fmaxf(xe + q0, 0.f); \
        acc1 += fmaxf(xe + q1, 0.f); \
        acc2 += fmaxf(xe + q2, 0.f); \
    } else { \
        const int base = (i) * SW; \
        const float q0 = Lf[base + lane]; \
        const float q1 = Lf[base + 64 + (lane & 31)]; \
        const float xe = xv##i; \
        acc0 += fmaxf(xe + q0, 0.f); \
        if (lane < 32) acc1 += fmaxf(xe + q1, 0.f); \
    } \
}

template<int NT, int XD>
__global__ __launch_bounds__(64, 2) void fused_edge_gather(
    const float* __restrict__ edge_attr, const int2* __restrict__ sedge,
    const int* __restrict__ dsta,
    const unsigned short* __restrict__ w1frag, const float* __restrict__ b1,
    const unsigned short* __restrict__ vfrag,  const float* __restrict__ bias2,
    const float* __restrict__ X, float* __restrict__ agg, int nChunks)
{
    constexpr int  C  = NT * 16;
    constexpr bool PK = (NT == 12);                  // packed-bf16 spill
    constexpr int  SW = PK ? 104 : (C + 2);          // words per edge row (bank-tiled)
    __shared__ unsigned int lds[16 * SW];            // one wave per block
    const int lane = threadIdx.x & 63;
    const int col  = lane & 15;
    const int quad = lane >> 4;
    const int cw   = blockIdx.x;
    if (cw >= nChunks) return;
    unsigned int* Lu = lds;
    float*        Lf = (float*)Lu;

    bf16x8 w1f[4];
#pragma unroll
    for (int tt = 0; tt < 4; tt++)
        w1f[tt] = *(const bf16x8*)(w1frag + (tt * 64 + lane) * 8);
    float4 b1v[4];
#pragma unroll
    for (int tt = 0; tt < 4; tt++)
        b1v[tt] = *(const float4*)(b1 + tt * 16 + quad * 4);
    float b2v[NT];
#pragma unroll
    for (int nt = 0; nt < NT; nt++) b2v[nt] = bias2[nt * 16 + col];

    const int xl = lane & (XD - 1);
    float acc0 = 0.f, acc1 = 0.f, acc2 = 0.f;
    int  curd  = -1;
    bool inside = false;

    auto do_flush = [&](bool atomicPath) {
        float* row = agg + (size_t)curd * C;
        if (!atomicPath) {
            row[lane] = acc0;
            if constexpr (PK) { row[64 + lane] = acc1; row[128 + lane] = acc2; }
            else { if (lane < 32) row[64 + lane] = acc1; }
        } else {
            atomicAdd(&row[lane], acc0);
            if constexpr (PK) { atomicAdd(&row[64 + lane], acc1); atomicAdd(&row[128 + lane], acc2); }
            else { if (lane < 32) atomicAdd(&row[64 + lane], acc1); }
        }
    };

    const int t0 = cw * CT;
    int2 se = sedge[(size_t)t0 * 16 + col];
    int  dv = dsta[(size_t)t0 * 16 + col];

    // ---- prologue: issue tile-0's scattered edge_attr raw loads ----
    float4 er0 = {0.f, 0.f, 0.f, 0.f}, er1 = {0.f, 0.f, 0.f, 0.f};
    if (quad < 2) {
        const int e0 = se.y;
        er0 = *(const float4*)(edge_attr + (size_t)e0 * 16 + quad * 8);
        er1 = *(const float4*)(edge_attr + (size_t)e0 * 16 + quad * 8 + 4);
    }

    for (int ti = 0; ti < CT; ++ti) {
        const int s = (t0 + ti) * 16 + col;

        // ---- prefetch next tile's edge metadata ----
        int2 se_n = se; int dv_n = dv;
        if (ti + 1 < CT) { se_n = sedge[s + 16]; dv_n = dsta[s + 16]; }

        // ---- 16 scattered X-row loads issued FIRST: in flight across MFMA A+B ----
        XLOAD(0)  XLOAD(1)  XLOAD(2)  XLOAD(3)
        XLOAD(4)  XLOAD(5)  XLOAD(6)  XLOAD(7)
        XLOAD(8)  XLOAD(9)  XLOAD(10) XLOAD(11)
        XLOAD(12) XLOAD(13) XLOAD(14) XLOAD(15)

        // ---- pack ea (waits only the ea loads — oldest outstanding) ----
        uint4 eau = make_uint4(0u, 0u, 0u, 0u);
        if (quad < 2) {
            eau.x = packbf2(er0.x, er0.y); eau.y = packbf2(er0.z, er0.w);
            eau.z = packbf2(er1.x, er1.y); eau.w = packbf2(er1.z, er1.w);
        }
        const bf16x8 eaf = __builtin_bit_cast(bf16x8, eau);

        // ---- edge MLP layer A ----
        __builtin_amdgcn_s_setprio(1);
        f32x4 c1[4];
#pragma unroll
        for (int tt = 0; tt < 4; tt++) {
            f32x4 ci = {b1v[tt].x, b1v[tt].y, b1v[tt].z, b1v[tt].w};
            c1[tt] = __builtin_amdgcn_mfma_f32_16x16x32_bf16(w1f[tt], eaf, ci, 0, 0, 0);
        }
        __builtin_amdgcn_s_setprio(0);
        bf16x8 a2[2];
#pragma unroll
        for (int ka = 0; ka < 2; ka++) {
            uint4 au;
            au.x = packbf2(fmaxf(c1[2 * ka][0], 0.f),     fmaxf(c1[2 * ka][1], 0.f));
            au.y = packbf2(fmaxf(c1[2 * ka][2], 0.f),     fmaxf(c1[2 * ka][3], 0.f));
            au.z = packbf2(fmaxf(c1[2 * ka + 1][0], 0.f), fmaxf(c1[2 * ka + 1][1], 0.f));
            au.w = packbf2(fmaxf(c1[2 * ka + 1][2], 0.f), fmaxf(c1[2 * ka + 1][3], 0.f));
            a2[ka] = __builtin_bit_cast(bf16x8, au);
        }

        // ---- edge MLP layer B, V-frags streamed; spill to LDS ----
        __builtin_amdgcn_s_setprio(1);
        if constexpr (PK) {
            const unsigned int xr = (unsigned int)((quad & 1) << 4);
#pragma unroll
            for (int nt = 0; nt < 6; nt++) {
                const bf16x8 va0 = *(const bf16x8*)(vfrag + ((nt * 2 + 0) * 64 + lane) * 8);
                const bf16x8 va1 = *(const bf16x8*)(vfrag + ((nt * 2 + 1) * 64 + lane) * 8);
                f32x4 ca = {b2v[nt], b2v[nt], b2v[nt], b2v[nt]};
                ca = __builtin_amdgcn_mfma_f32_16x16x32_bf16(a2[0], va0, ca, 0, 0, 0);
                ca = __builtin_amdgcn_mfma_f32_16x16x32_bf16(a2[1], va1, ca, 0, 0, 0);
                const bf16x8 vb0 = *(const bf16x8*)(vfrag + (((nt + 6) * 2 + 0) * 64 + lane) * 8);
                const bf16x8 vb1 = *(const bf16x8*)(vfrag + (((nt + 6) * 2 + 1) * 64 + lane) * 8);
                f32x4 cb = {b2v[nt + 6], b2v[nt + 6], b2v[nt + 6], b2v[nt + 6]};
                cb = __builtin_amdgcn_mfma_f32_16x16x32_bf16(a2[0], vb0, cb, 0, 0, 0);
                cb = __builtin_amdgcn_mfma_f32_16x16x32_bf16(a2[1], vb1, cb, 0, 0, 0);
#pragma unroll
                for (int r = 0; r < 4; r++)
                    Lu[(quad * 4 + r) * SW + (((unsigned)(nt * 16 + col)) ^ xr)] =
                        packbf2(ca[r], cb[r]);
            }
        } else {
#pragma unroll
            for (int nt = 0; nt < NT; nt++) {
                const bf16x8 v0 = *(const bf16x8*)(vfrag + ((nt * 2 + 0) * 64 + lane) * 8);
                const bf16x8 v1 = *(const bf16x8*)(vfrag + ((nt * 2 + 1) * 64 + lane) * 8);
                f32x4 c = {b2v[nt], b2v[nt], b2v[nt], b2v[nt]};
                c = __builtin_amdgcn_mfma_f32_16x16x32_bf16(a2[0], v0, c, 0, 0, 0);
                c = __builtin_amdgcn_mfma_f32_16x16x32_bf16(a2[1], v1, c, 0, 0, 0);
#pragma unroll
                for (int r = 0; r < 4; r++)
                    Lf[(quad * 4 + r) * SW + nt * 16 + col] = c[r];
            }
        }
        __builtin_amdgcn_s_setprio(0);

        // ---- issue NEXT tile's edge_attr raw loads: covered by the walk ----
        if (ti + 1 < CT && quad < 2) {
            const int en = se_n.y;
            er0 = *(const float4*)(edge_attr + (size_t)en * 16 + quad * 8);
            er1 = *(const float4*)(edge_attr + (size_t)en * 16 + quad * 8 + 4);
        }

        // ---- segmented walk: LDS + VALU; dst via readlane (SALU) ----
        WSTEP(0)  WSTEP(1)  WSTEP(2)  WSTEP(3)
        WSTEP(4)  WSTEP(5)  WSTEP(6)  WSTEP(7)
        WSTEP(8)  WSTEP(9)  WSTEP(10) WSTEP(11)
        WSTEP(12) WSTEP(13) WSTEP(14) WSTEP(15)

        se = se_n; dv = dv_n;
    }
    do_flush(true);   // final open segment may continue into the next chunk
}
#undef XLOAD
#undef WSTEP

// ---------------- node MLP layer 1 via MFMA (16 nodes per wave) ----------------
__global__ __launch_bounds__(256) void mlp1_mfma_kernel(
    const float* __restrict__ x, const float* __restrict__ agg1,
    const unsigned short* __restrict__ fr2, const float* __restrict__ c1_b1,
    const float* __restrict__ fw, float* __restrict__ h1)
{
    const int lane = threadIdx.x & 63, wid = threadIdx.x >> 6;
    const int tile = blockIdx.x * 4 + wid;
    if (tile >= NTILES) return;
    const int col = lane & 15, quad = lane >> 4;
    const int node = tile * 16 + col;

    const float4 xa = *(const float4*)(x + (size_t)node * 32 + quad * 8);
    const float4 xb = *(const float4*)(x + (size_t)node * 32 + quad * 8 + 4);

    f32x4 c2[4];
#pragma unroll
    for (int b = 0; b < 4; b++) {
        const float ub = fw[F_UB1 + b * 16 + col];
        c2[b] = {ub, ub, ub, ub};
    }
#pragma unroll
    for (int i = 0; i < 3; i++) {
        const float4 a0 = *(const float4*)(agg1 + (size_t)node * 96 + i * 32 + quad * 8);
        const float4 a1 = *(const float4*)(agg1 + (size_t)node * 96 + i * 32 + quad * 8 + 4);
        uint4 iu;
        iu.x = packbf2(xa.x + a0.x, xa.y + a0.y);
        iu.y = packbf2(xa.z + a0.z, xa.w + a0.w);
        iu.z = packbf2(xb.x + a1.x, xb.y + a1.y);
        iu.w = packbf2(xb.z + a1.z, xb.w + a1.w);
        const bf16x8 inf = __builtin_bit_cast(bf16x8, iu);

        f32x4 c1[4];
#pragma unroll
        for (int tt = 0; tt < 4; tt++) {
            const bf16x8 wf = *(const bf16x8*)(fr2 + FR3_M1W + ((i * 4 + tt) * 64 + lane) * 8);
            const float4 bi = *(const float4*)(c1_b1 + i * 64 + tt * 16 + quad * 4);
            f32x4 ci = {bi.x, bi.y, bi.z, bi.w};
            c1[tt] = __builtin_amdgcn_mfma_f32_16x16x32_bf16(wf, inf, ci, 0, 0, 0);
        }
        bf16x8 a2[2];
#pragma unroll
        for (int ka = 0; ka < 2; ka++) {
            uint4 au;
            au.x = packbf2(fmaxf(c1[2 * ka][0], 0.f),     fmaxf(c1[2 * ka][1], 0.f));
            au.y = packbf2(fmaxf(c1[2 * ka][2], 0.f),     fmaxf(c1[2 * ka][3], 0.f));
            au.z = packbf2(fmaxf(c1[2 * ka + 1][0], 0.f), fmaxf(c1[2 * ka + 1][1], 0.f));
            au.w = packbf2(fmaxf(c1[2 * ka + 1][2], 0.f), fmaxf(c1[2 * ka + 1][3], 0.f));
            a2[ka] = __builtin_bit_cast(bf16x8, au);
        }
#pragma unroll
        for (int b = 0; b < 4; b++)
#pragma unroll
            for (int ka = 0; ka < 2; ka++) {
                const bf16x8 uf = *(const bf16x8*)(fr2 + FR3_M1U + (((i * 4 + b) * 2 + ka) * 64 + lane) * 8);
                c2[b] = __builtin_amdgcn_mfma_f32_16x16x32_bf16(a2[ka], uf, c2[b], 0, 0, 0);
            }
    }
    const int rowb = tile * 16 + quad * 4;
#pragma unroll
    for (int b = 0; b < 4; b++)
#pragma unroll
        for (int r = 0; r < 4; r++)
            h1[(size_t)(rowb + r) * 64 + b * 16 + col] = fmaxf(c2[b][r], 0.f);
}

// ---------------- node MLP layer 2 via MFMA (16 nodes per wave) ----------------
__global__ __launch_bounds__(256) void mlp2_mfma_kernel(
    const float* __restrict__ h1, const float* __restrict__ agg2,
    const unsigned short* __restrict__ fr2, const float* __restrict__ c2_b1,
    const float* __restrict__ fw, float* __restrict__ h2)
{
    const int lane = threadIdx.x & 63, wid = threadIdx.x >> 6;
    const int tile = blockIdx.x * 4 + wid;
    if (tile >= NTILES) return;
    const int col = lane & 15, quad = lane >> 4;
    const int node = tile * 16 + col;

    float4 hv[4];
#pragma unroll
    for (int p = 0; p < 4; p++)
        hv[p] = *(const float4*)(h1 + (size_t)node * 64 + (p >> 1) * 32 + quad * 8 + (p & 1) * 4);

    f32x4 c2[4];
#pragma unroll
    for (int b = 0; b < 4; b++) {
        const float ub = fw[F_UB2 + b * 16 + col];
        c2[b] = {ub, ub, ub, ub};
    }
#pragma unroll
    for (int i = 0; i < 3; i++) {
        bf16x8 inf[2];
#pragma unroll
        for (int ka = 0; ka < 2; ka++) {
            const float4 a0 = *(const float4*)(agg2 + (size_t)node * 192 + i * 64 + ka * 32 + quad * 8);
            const float4 a1 = *(const float4*)(agg2 + (size_t)node * 192 + i * 64 + ka * 32 + quad * 8 + 4);
            const float4 h0 = hv[ka * 2], h1v = hv[ka * 2 + 1];
            uint4 iu;
            iu.x = packbf2(h0.x + a0.x, h0.y + a0.y);
            iu.y = packbf2(h0.z + a0.z, h0.w + a0.w);
            iu.z = packbf2(h1v.x + a1.x, h1v.y + a1.y);
            iu.w = packbf2(h1v.z + a1.z, h1v.w + a1.w);
            inf[ka] = __builtin_bit_cast(bf16x8, iu);
        }
        f32x4 c1[4];
#pragma unroll
        for (int tt = 0; tt < 4; tt++) {
            const bf16x8 wf0 = *(const bf16x8*)(fr2 + FR3_M2W + (((i * 4 + tt) * 2 + 0) * 64 + lane) * 8);
            const bf16x8 wf1 = *(const bf16x8*)(fr2 + FR3_M2W + (((i * 4 + tt) * 2 + 1) * 64 + lane) * 8);
            const float4 bi = *(const float4*)(c2_b1 + i * 64 + tt * 16 + quad * 4);
            f32x4 ci = {bi.x, bi.y, bi.z, bi.w};
            ci = __builtin_amdgcn_mfma_f32_16x16x32_bf16(wf0, inf[0], ci, 0, 0, 0);
            c1[tt] = __builtin_amdgcn_mfma_f32_16x16x32_bf16(wf1, inf[1], ci, 0, 0, 0);
        }
        bf16x8 a2[2];
#pragma unroll
        for (int ka = 0; ka < 2; ka++) {
            uint4 au;
            au.x = packbf2(fmaxf(c1[2 * ka][0], 0.f),     fmaxf(c1[2 * ka][1], 0.f));
            au.y = packbf2(fmaxf(c1[2 * ka][2], 0.f),     fmaxf(c1[2 * ka][3], 0.f));
            au.z = packbf2(fmaxf(c1[2 * ka + 1][0], 0.f), fmaxf(c1[2 * ka + 1][1], 0.f));
            au.w = packbf2(fmaxf(c1[2 * ka + 1][2], 0.f), fmaxf(c1[2 * ka + 1][3], 0.f));
            a2[ka] = __builtin_bit_cast(bf16x8, au);
        }
#pragma unroll
        for (int b = 0; b < 4; b++)
#pragma unroll
            for (int ka = 0; ka < 2; ka++) {
                const bf16x8 uf = *(const bf16x8*)(fr2 + FR3_M2U + (((i * 4 + b) * 2 + ka) * 64 + lane) * 8);
                c2[b] = __builtin_amdgcn_mfma_f32_16x16x32_bf16(a2[ka], uf, c2[b], 0, 0, 0);
            }
    }
    const int rowb = tile * 16 + quad * 4;
#pragma unroll
    for (int b = 0; b < 4; b++)
#pragma unroll
        for (int r = 0; r < 4; r++)
            h2[(size_t)(rowb + r) * 64 + b * 16 + col] = fmaxf(c2[b][r], 0.f);
}

// ---------------- pooling + head (fused; batch is sorted) ----------------
__global__ __launch_bounds__(256) void pool_kernel(
    const float* __restrict__ h2, const int* __restrict__ batch,
    const float* __restrict__ u, const float* __restrict__ fc_w,
    const float* __restrict__ fc_b, float* __restrict__ out)
{
    __shared__ float red[256];
    const int g = blockIdx.x, t = threadIdx.x;
    int lo = 0, hi = N_NODES;
    while (lo < hi) { int m = (lo + hi) >> 1; if (batch[m] < g) lo = m + 1; else hi = m; }
    int lo2 = lo, hi2 = N_NODES;
    while (lo2 < hi2) { int m = (lo2 + hi2) >> 1; if (batch[m] < g + 1) lo2 = m + 1; else hi2 = m; }

    const int col = t & 63, ch = t >> 6;
    float s = 0.f;
    for (int idx = lo + ch; idx < lo2; idx += 4) s += h2[(size_t)idx * 64 + col];
    red[t] = s;
    __syncthreads();
    if (t < 64) red[t] = red[t] + red[64 + t] + red[128 + t] + red[192 + t];
    __syncthreads();
    if (t == 0) {
        const float inv = 1.f / fmaxf((float)(lo2 - lo), 1.f);
        float sv = fc_b[0];
        for (int j = 0; j < 64; j++) sv = fmaf(red[j] * inv, fc_w[j], sv);
        for (int k = 0; k < 32; k++) sv = fmaf(u[(size_t)g * 32 + k], fc_w[64 + k], sv);
        out[g] = sv;
    }
}

extern "C" void kernel_launch(void* const* d_in, const int* in_sizes, int n_in,
                              void* d_out, int out_size, void* d_ws, size_t ws_size,
                              hipStream_t stream) {
    (void)in_sizes; (void)n_in; (void)out_size; (void)ws_size;
    const float* x        = (const float*)d_in[0];
    const float* edge_attr= (const float*)d_in[1];
    const float* u        = (const float*)d_in[2];
    const float* em1_w1   = (const float*)d_in[3];
    const float* em1_b1   = (const float*)d_in[4];
    const float* em1_w2   = (const float*)d_in[5];
    const float* em1_b2   = (const float*)d_in[6];
    const float* em2_w1   = (const float*)d_in[7];
    const float* em2_b1   = (const float*)d_in[8];
    const float* em2_w2   = (const float*)d_in[9];
    const float* em2_b2   = (const float*)d_in[10];
    const float* c1_lin_w = (const float*)d_in[11];
    const float* c1_lin_b = (const float*)d_in[12];
    const float* c1_w1    = (const float*)d_in[13];
    const float* c1_b1    = (const float*)d_in[14];
    const float* c1_w2    = (const float*)d_in[15];
    const float* c1_b2    = (const float*)d_in[16];
    const float* c2_lin_w = (const float*)d_in[17];
    const float* c2_lin_b = (const float*)d_in[18];
    const float* c2_w1    = (const float*)d_in[19];
    const float* c2_b1    = (const float*)d_in[20];
    const float* c2_w2    = (const float*)d_in[21];
    const float* c2_b2    = (const float*)d_in[22];
    const float* lin1_w   = (const float*)d_in[23];
    const float* lin1_b   = (const float*)d_in[24];
    const float* lin2_w   = (const float*)d_in[25];
    const float* lin2_b   = (const float*)d_in[26];
    const float* fc_w     = (const float*)d_in[27];
    const float* fc_b     = (const float*)d_in[28];
    const int*   ei       = (const int*)d_in[29];
    const int*   batch    = (const int*)d_in[30];

    char* wsb = (char*)d_ws;
    int*   cnt  = (int*)(wsb + B_CNT);
    int*   off  = (int*)(wsb + B_OFF);
    int*   cur  = (int*)(wsb + B_CUR);
    int*   bsum = (int*)(wsb + B_BSUM);
    int2*  sedge= (int2*)(wsb + B_SEDGE);
    int*   dsta = (int*)(wsb + B_DSTA);
    float* agg  = (float*)(wsb + B_AGG);    // [N][96] for layer1, [N][192] for layer2
    float* h1   = (float*)(wsb + B_H1);
    float* h2   = (float*)(wsb + B_H2);
    float* fw   = (float*)(wsb + B_FOLD);
    unsigned short* fr  = (unsigned short*)(wsb + B_FRAG);
    unsigned short* fr2 = (unsigned short*)(wsb + B_FR2);
    float* out  = (float*)d_out;

    (void)hipMemsetAsync(d_ws, 0, ZERO_BYTES, stream);   // histogram counters only

    fold_kernel<<<(FOLD_TOTAL + 255) / 256, 256, 0, stream>>>(
        em1_w2, em1_b2, em2_w2, em2_b2, c1_lin_w, c1_lin_b, c2_lin_w, c2_lin_b,
        c1_w2, c1_b2, c2_w2, c2_b2, lin1_w, lin1_b, lin2_w, lin2_b, fw);
    fold2_kernel<<<(FOLD2_TOTAL + 255) / 256, 256, 0, stream>>>(em1_w1, em2_w1, fw, fr);
    fold3_kernel<<<(FOLD3_TOTAL + 255) / 256, 256, 0, stream>>>(c1_w1, c2_w1, fw, fr2);

    // counting sort by dst
    hist_kernel<<<N_EDGES / 256, 256, 0, stream>>>(ei, cnt);
    scan1_kernel<<<196, 256, 0, stream>>>(cnt, off, bsum);
    scan2_kernel<<<1, 256, 0, stream>>>(bsum);
    scan3_kernel<<<196, 256, 0, stream>>>(off, bsum, cur);
    scatter_kernel<<<N_EDGES / 256, 256, 0, stream>>>(ei, cur, sedge, dsta);

    // layer 1: fused edge MLP + segmented gather (q never hits HBM)
    (void)hipMemsetAsync(wsb + B_AGG, 0, (size_t)N_NODES * 96 * 4, stream);
    fused_edge_gather<6, 32><<<NCHUNKS, 64, 0, stream>>>(
        edge_attr, sedge, dsta, fr + FR_W1E1, em1_b1, fr + FR_V1, fw + F_B1F, x, agg, NCHUNKS);
    mlp1_mfma_kernel<<<(NTILES + 3) / 4, 256, 0, stream>>>(x, agg, fr2, c1_b1, fw, h1);

    // layer 2
    (void)hipMemsetAsync(wsb + B_AGG, 0, (size_t)N_NODES * 192 * 4, stream);
    fused_edge_gather<12, 64><<<NCHUNKS, 64, 0, stream>>>(
        edge_attr, sedge, dsta, fr + FR_W1E2, em2_b1, fr + FR_V2, fw + F_B2F, h1, agg, NCHUNKS);
    mlp2_mfma_kernel<<<(NTILES + 3) / 4, 256, 0, stream>>>(h1, agg, fr2, c2_b1, fw, h2);

    // pooling + head (fused)
    pool_kernel<<<N_GRAPHS, 256, 0, stream>>>(h2, batch, u, fc_w, fc_b, out);
}

// Round 12
// 453.040 us; speedup vs baseline: 1.0445x; 1.0038x over previous
//
#include <hip/hip_runtime.h>
#include <hip/hip_bf16.h>

#define N_NODES  50000
#define N_EDGES  800000
#define N_GRAPHS 512
#define NTILES   3125   // N_NODES / 16
#define ETILES   50000  // N_EDGES / 16
#define CT       4      // edge tiles per wave chunk
#define NCHUNKS  (ETILES / CT)   // 12500

typedef short bf16x8 __attribute__((ext_vector_type(8)));
typedef float f32x4  __attribute__((ext_vector_type(4)));

// ---------------- workspace layout (BYTE offsets, 256-aligned) ----------------
constexpr size_t B_CNT  = 0;                 // N ints (zeroed)
constexpr size_t ZERO_BYTES = 200192;
constexpr size_t B_OFF  = 200192;            // (N+1) ints
constexpr size_t B_CUR  = 400384;            // N ints
constexpr size_t B_BSUM = 600576;            // 256 ints
constexpr size_t B_SEDGE= 601600;            // E int2 (src, eid) sorted by dst — 6.4 MB
constexpr size_t B_DSTA = 7001600;           // E ints: dst of sorted edge — 3.2 MB
constexpr size_t B_FR2  = 10201600;          // mlp MFMA frags, 43008 ushorts
constexpr size_t B_AGG  = 10287616;          // N*192 f (layer2); aliased as [N][96] (layer1)
constexpr size_t B_H1   = 48687616;          // N*64 f
constexpr size_t B_H2   = 61487616;          // N*64 f
constexpr size_t B_FOLD = 74287616;          // folded weights, 43424 floats
constexpr size_t B_FRAG = 74461440;          // bf16 edge-MFMA fragment weights (22528 ushorts)
// fold-region float offsets
constexpr int F_V1H = 0;      // [64][96]   V1[t][n]
constexpr int F_B1F = 6144;   // [96]
constexpr int F_V2H = 6240;   // [64][192]  V2[t][n]
constexpr int F_B2F = 18528;  // [192]
constexpr int F_U1  = 18720;  // [3][64][64]
constexpr int F_UB1 = 31008;  // [64]
constexpr int F_U2  = 31072;  // [3][64][64]
constexpr int F_UB2 = 43360;  // [64]
constexpr int FOLD_TOTAL = 43424;
// edge frag-region ushort offsets
constexpr int FR_W1E1 = 0;      // [4][64][8]   em1_w1^T A-frags (K padded 16->32)
constexpr int FR_W1E2 = 2048;   // [4][64][8]
constexpr int FR_V1   = 4096;   // [6][2][64][8]  V1 B-frags, k-permuted
constexpr int FR_V2   = 10240;  // [12][2][64][8] V2 B-frags, k-permuted
constexpr int FOLD2_TOTAL = 22528;
// mlp frag-region (fr2) ushort offsets
constexpr int FR3_M1W = 0;      // [3][4][64][8]     c1_w1^T A-frags (K=32)
constexpr int FR3_M1U = 6144;   // [3][4][2][64][8]  U1 B-frags, k-permuted
constexpr int FR3_M2W = 18432;  // [3][4][2][64][8]  c2_w1^T A-frags (K=64)
constexpr int FR3_M2U = 30720;  // [3][4][2][64][8]  U2 B-frags, k-permuted
constexpr int FOLD3_TOTAL = 43008;

__device__ inline unsigned short bf16u(float x) {
    unsigned int ua = __float_as_uint(x);
    return (unsigned short)((ua + 0x7FFFu + ((ua >> 16) & 1u)) >> 16);
}
// cold-path manual pack (fold kernels only)
__device__ inline unsigned int packbf2(float a, float b) {
    unsigned int ua = __float_as_uint(a), ub = __float_as_uint(b);
    return ((ua + 0x7FFFu + ((ua >> 16) & 1u)) >> 16) |
           ((ub + 0x7FFFu + ((ub >> 16) & 1u)) & 0xFFFF0000u);
}
// hot-path pack: compiler-emitted RN conversions (clang fuses the f32->bf16
// trunc pair + pack into v_cvt_pk_bf16_f32 on gfx950 where legal — m240:
// scalar casts beat hand-written asm, which failed correctness in round 11).
__device__ inline unsigned int pkbf16(float a, float b) {
    unsigned short lo = __builtin_bit_cast(unsigned short, __float2bfloat16(a));
    unsigned short hi = __builtin_bit_cast(unsigned short, __float2bfloat16(b));
    return (unsigned int)lo | ((unsigned int)hi << 16);
}

// ---------------- fold: precompute folded weight products (fp32) ----------------
__global__ __launch_bounds__(256) void fold_kernel(
    const float* __restrict__ em1_w2, const float* __restrict__ em1_b2,
    const float* __restrict__ em2_w2, const float* __restrict__ em2_b2,
    const float* __restrict__ c1_lin_w, const float* __restrict__ c1_lin_b,
    const float* __restrict__ c2_lin_w, const float* __restrict__ c2_lin_b,
    const float* __restrict__ c1_w2, const float* __restrict__ c1_b2,
    const float* __restrict__ c2_w2, const float* __restrict__ c2_b2,
    const float* __restrict__ lin1_w, const float* __restrict__ lin1_b,
    const float* __restrict__ lin2_w, const float* __restrict__ lin2_b,
    float* __restrict__ fw)
{
    int idx = blockIdx.x * 256 + threadIdx.x;
    if (idx >= FOLD_TOTAL) return;
    int r = idx;
    if (r < 6144) {
        int k = r / 96, c = r % 96, i = c / 32, j = c % 32;
        float s = 0.f;
        for (int m = 0; m < 64; m++) s = fmaf(em1_w2[k * 64 + m], c1_lin_w[i * 2048 + m * 32 + j], s);
        fw[F_V1H + r] = s; return;
    }
    r -= 6144;
    if (r < 96) {
        int i = r / 32, j = r % 32;
        float s = c1_lin_b[r];
        for (int m = 0; m < 64; m++) s = fmaf(em1_b2[m], c1_lin_w[i * 2048 + m * 32 + j], s);
        fw[F_B1F + r] = s; return;
    }
    r -= 96;
    if (r < 12288) {
        int k = r / 192, c = r % 192, i = c / 64, j = c % 64;
        float s = 0.f;
        for (int m = 0; m < 64; m++) s = fmaf(em2_w2[k * 64 + m], c2_lin_w[i * 4096 + m * 64 + j], s);
        fw[F_V2H + r] = s; return;
    }
    r -= 12288;
    if (r < 192) {
        int i = r / 64, j = r % 64;
        float s = c2_lin_b[r];
        for (int m = 0; m < 64; m++) s = fmaf(em2_b2[m], c2_lin_w[i * 4096 + m * 64 + j], s);
        fw[F_B2F + r] = s; return;
    }
    r -= 192;
    if (r < 12288) {
        int i = r / 4096, k = (r / 64) % 64, j = r % 64;
        float s = 0.f;
        for (int m = 0; m < 64; m++) s = fmaf(c1_w2[i * 4096 + k * 64 + m], lin1_w[(i * 64 + m) * 64 + j], s);
        fw[F_U1 + r] = s; return;
    }
    r -= 12288;
    if (r < 64) {
        float s = lin1_b[r];
        for (int i = 0; i < 3; i++)
            for (int m = 0; m < 64; m++) s = fmaf(c1_b2[i * 64 + m], lin1_w[(i * 64 + m) * 64 + r], s);
        fw[F_UB1 + r] = s; return;
    }
    r -= 64;
    if (r < 12288) {
        int i = r / 4096, k = (r / 64) % 64, j = r % 64;
        float s = 0.f;
        for (int m = 0; m < 64; m++) s = fmaf(c2_w2[i * 4096 + k * 64 + m], lin2_w[(i * 64 + m) * 64 + j], s);
        fw[F_U2 + r] = s; return;
    }
    r -= 12288;
    {
        float s = lin2_b[r];
        for (int i = 0; i < 3; i++)
            for (int m = 0; m < 64; m++) s = fmaf(c2_b2[i * 64 + m], lin2_w[(i * 64 + m) * 64 + r], s);
        fw[F_UB2 + r] = s; return;
    }
}

// ---------------- fold2: edge-MFMA bf16 fragment weights ----------------
__global__ __launch_bounds__(256) void fold2_kernel(
    const float* __restrict__ em1_w1, const float* __restrict__ em2_w1,
    const float* __restrict__ fw, unsigned short* __restrict__ fr)
{
    int idx = blockIdx.x * 256 + threadIdx.x;
    if (idx >= FOLD2_TOTAL) return;
    if (idx < 4096) {
        const float* w = (idx < 2048) ? em1_w1 : em2_w1;
        int r = idx & 2047;
        int tt = r >> 9, lane = (r >> 3) & 63, j = r & 7;
        int q = lane >> 4, k = q * 8 + j, m = tt * 16 + (lane & 15);
        fr[idx] = (k < 16) ? bf16u(w[k * 64 + m]) : (unsigned short)0;
        return;
    }
    if (idx < 10240) {
        int r = idx - 4096;
        int nt = r / 1024, ka = (r >> 9) & 1, lane = (r >> 3) & 63, j = r & 7;
        int q = lane >> 4;
        int t = 32 * ka + 16 * (j >> 2) + 4 * q + (j & 3);
        int n = nt * 16 + (lane & 15);
        fr[idx] = bf16u(fw[F_V1H + t * 96 + n]);
        return;
    }
    {
        int r = idx - 10240;
        int nt = r / 1024, ka = (r >> 9) & 1, lane = (r >> 3) & 63, j = r & 7;
        int q = lane >> 4;
        int t = 32 * ka + 16 * (j >> 2) + 4 * q + (j & 3);
        int n = nt * 16 + (lane & 15);
        fr[idx] = bf16u(fw[F_V2H + t * 192 + n]);
        return;
    }
}

// ---------------- fold3: node-MLP MFMA fragments ----------------
__global__ __launch_bounds__(256) void fold3_kernel(
    const float* __restrict__ c1_w1, const float* __restrict__ c2_w1,
    const float* __restrict__ fw, unsigned short* __restrict__ fr2)
{
    int idx = blockIdx.x * 256 + threadIdx.x;
    if (idx >= FOLD3_TOTAL) return;
    if (idx < 6144) {
        int i = idx / 2048, r = idx % 2048;
        int tt = r >> 9, lane = (r >> 3) & 63, jj = r & 7;
        int k = (lane >> 4) * 8 + jj, m = tt * 16 + (lane & 15);
        fr2[FR3_M1W + idx] = bf16u(c1_w1[i * 2048 + k * 64 + m]);
        return;
    }
    if (idx < 18432) {
        int r = idx - 6144;
        int i = r / 4096, r2 = r % 4096;
        int b = r2 >> 10, ka = (r2 >> 9) & 1, lane = (r2 >> 3) & 63, jj = r2 & 7;
        int t = 32 * ka + 16 * (jj >> 2) + 4 * (lane >> 4) + (jj & 3);
        int n = b * 16 + (lane & 15);
        fr2[FR3_M1U + r] = bf16u(fw[F_U1 + i * 4096 + t * 64 + n]);
        return;
    }
    if (idx < 30720) {
        int r = idx - 18432;
        int i = r / 4096, r2 = r % 4096;
        int tt = r2 >> 10, ka = (r2 >> 9) & 1, lane = (r2 >> 3) & 63, jj = r2 & 7;
        int k = ka * 32 + (lane >> 4) * 8 + jj, m = tt * 16 + (lane & 15);
        fr2[FR3_M2W + r] = bf16u(c2_w1[i * 4096 + k * 64 + m]);
        return;
    }
    {
        int r = idx - 30720;
        int i = r / 4096, r2 = r % 4096;
        int b = r2 >> 10, ka = (r2 >> 9) & 1, lane = (r2 >> 3) & 63, jj = r2 & 7;
        int t = 32 * ka + 16 * (jj >> 2) + 4 * (lane >> 4) + (jj & 3);
        int n = b * 16 + (lane & 15);
        fr2[FR3_M2U + r] = bf16u(fw[F_U2 + i * 4096 + t * 64 + n]);
        return;
    }
}

// ---------------- counting sort: hist -> scan -> scatter ----------------
__global__ __launch_bounds__(256) void hist_kernel(const int* __restrict__ ei, int* __restrict__ cnt) {
    int e = blockIdx.x * 256 + threadIdx.x;
    if (e < N_EDGES) atomicAdd(&cnt[ei[N_EDGES + e]], 1);
}

__global__ __launch_bounds__(256) void scan1_kernel(const int* __restrict__ cnt,
                                                    int* __restrict__ off, int* __restrict__ bsum) {
    __shared__ int sh[256];
    int t = threadIdx.x, i = blockIdx.x * 256 + t;
    int v = (i < N_NODES) ? cnt[i] : 0;
    sh[t] = v; __syncthreads();
    for (int d = 1; d < 256; d <<= 1) {
        int add = (t >= d) ? sh[t - d] : 0;
        __syncthreads();
        sh[t] += add;
        __syncthreads();
    }
    if (i < N_NODES) off[i] = sh[t] - v;
    if (t == 255) bsum[blockIdx.x] = sh[255];
}

__global__ __launch_bounds__(256) void scan2_kernel(int* __restrict__ bsum) {
    __shared__ int sh[256];
    int t = threadIdx.x;
    int v = (t < 196) ? bsum[t] : 0;
    sh[t] = v; __syncthreads();
    for (int d = 1; d < 256; d <<= 1) {
        int add = (t >= d) ? sh[t - d] : 0;
        __syncthreads();
        sh[t] += add;
        __syncthreads();
    }
    bsum[t] = sh[t] - v;
}

__global__ __launch_bounds__(256) void scan3_kernel(int* __restrict__ off, const int* __restrict__ bsum,
                                                    int* __restrict__ cur) {
    int i = blockIdx.x * 256 + threadIdx.x;
    if (i < N_NODES) {
        int o = off[i] + bsum[i >> 8];
        off[i] = o;
        cur[i] = o;
    }
    if (i == 0) off[N_NODES] = N_EDGES;
}

// scatter also records dst per sorted slot (needed by fused gather for segment bounds)
__global__ __launch_bounds__(256) void scatter_kernel(const int* __restrict__ ei, int* __restrict__ cur,
                                                      int2* __restrict__ sedge, int* __restrict__ dsta) {
    int e = blockIdx.x * 256 + threadIdx.x;
    if (e >= N_EDGES) return;
    int d = ei[N_EDGES + e];
    int p = atomicAdd(&cur[d], 1);
    sedge[p] = make_int2(ei[e], e);
    dsta[p] = d;
}

// ---------------- FUSED edge-projection MFMA + segmented gather (v11) --------
// v10 post-mortem: hand-asm v_cvt_pk_bf16_f32 produced garbage (absmax 1.7e35)
// — semantics mismatch. v11 = v9 (454.8us, passing) + pkbf16 via compiler
// __float2bfloat16 RN casts (clang fuses the pair into the pk instruction
// where legal; worst case 3 ops vs 9 manual). Numerics identical (RTNE).
#define XLOAD(i) const float xv##i = X[(size_t)__builtin_amdgcn_readlane(se.x, i) * XD + xl];
#define WSTEP(i) { \
    const int dnn = __builtin_amdgcn_readlane(dv, i); \
    if (dnn != curd) { \
        if (curd >= 0) { do_flush(!inside); inside = true; } \
        curd = dnn; \
        acc0 = acc1 = acc2 = 0.f; \
    } \
    if constexpr (PK) { \
        const int base = (i) * SW; \
        const unsigned int xr = (unsigned int)((((i) >> 2) & 1) << 4); \
        const unsigned int w0 = Lu[base + (((unsigned)lane) ^ xr)]; \
        const int i1 = (lane < 32) ? (lane + 64) : (lane - 32); \
        const unsigned int w1 = Lu[base + (((unsigned)i1) ^ xr)]; \
        const unsigned int w2 = Lu[base + (((unsigned)(lane + 32)) ^ xr)]; \
        const float q0 = __uint_as_float(w0 << 16); \
        const float q1 = (lane < 32) ? __uint_as_float(w1 << 16) \
                                     : __uint_as_float(w1 & 0xFFFF0000u); \
        const float q2 = __uint_as_float(w2 & 0xFFFF0000u); \
        const float xe = xv##i; \
        acc0 += fmaxf(xe + q0, 0.f); \
        acc1 += fmaxf(xe + q1, 0.f); \
        acc2 += fmaxf(xe + q2, 0.f); \
    } else { \
        const int base = (i) * SW; \
        const float q0 = Lf[base + lane]; \
        const float q1 = Lf[base + 64 + (lane & 31)]; \
        const float xe = xv##i; \
        acc0 += fmaxf(xe + q0, 0.f); \
        if (lane < 32) acc1 += fmaxf(xe + q1, 0.f); \
    } \
}

template<int NT, int XD>
__global__ __launch_bounds__(64, 2) void fused_edge_gather(
    const float* __restrict__ edge_attr, const int2* __restrict__ sedge,
    const int* __restrict__ dsta,
    const unsigned short* __restrict__ w1frag, const float* __restrict__ b1,
    const unsigned short* __restrict__ vfrag,  const float* __restrict__ bias2,
    const float* __restrict__ X, float* __restrict__ agg, int nChunks)
{
    constexpr int  C  = NT * 16;
    constexpr bool PK = (NT == 12);                  // packed-bf16 spill
    constexpr int  SW = PK ? 104 : (C + 2);          // words per edge row (bank-tiled)
    __shared__ unsigned int lds[16 * SW];            // one wave per block
    const int lane = threadIdx.x & 63;
    const int col  = lane & 15;
    const int quad = lane >> 4;
    const int cw   = blockIdx.x;
    if (cw >= nChunks) return;
    unsigned int* Lu = lds;
    float*        Lf = (float*)Lu;

    bf16x8 w1f[4];
#pragma unroll
    for (int tt = 0; tt < 4; tt++)
        w1f[tt] = *(const bf16x8*)(w1frag + (tt * 64 + lane) * 8);
    float4 b1v[4];
#pragma unroll
    for (int tt = 0; tt < 4; tt++)
        b1v[tt] = *(const float4*)(b1 + tt * 16 + quad * 4);
    float b2v[NT];
#pragma unroll
    for (int nt = 0; nt < NT; nt++) b2v[nt] = bias2[nt * 16 + col];

    const int xl = lane & (XD - 1);
    float acc0 = 0.f, acc1 = 0.f, acc2 = 0.f;
    int  curd  = -1;
    bool inside = false;

    auto do_flush = [&](bool atomicPath) {
        float* row = agg + (size_t)curd * C;
        if (!atomicPath) {
            row[lane] = acc0;
            if constexpr (PK) { row[64 + lane] = acc1; row[128 + lane] = acc2; }
            else { if (lane < 32) row[64 + lane] = acc1; }
        } else {
            atomicAdd(&row[lane], acc0);
            if constexpr (PK) { atomicAdd(&row[64 + lane], acc1); atomicAdd(&row[128 + lane], acc2); }
            else { if (lane < 32) atomicAdd(&row[64 + lane], acc1); }
        }
    };

    const int t0 = cw * CT;
    int2 se = sedge[(size_t)t0 * 16 + col];
    int  dv = dsta[(size_t)t0 * 16 + col];

    // ---- prologue: issue tile-0's scattered edge_attr raw loads ----
    float4 er0 = {0.f, 0.f, 0.f, 0.f}, er1 = {0.f, 0.f, 0.f, 0.f};
    if (quad < 2) {
        const int e0 = se.y;
        er0 = *(const float4*)(edge_attr + (size_t)e0 * 16 + quad * 8);
        er1 = *(const float4*)(edge_attr + (size_t)e0 * 16 + quad * 8 + 4);
    }

    for (int ti = 0; ti < CT; ++ti) {
        const int s = (t0 + ti) * 16 + col;

        // ---- prefetch next tile's edge metadata ----
        int2 se_n = se; int dv_n = dv;
        if (ti + 1 < CT) { se_n = sedge[s + 16]; dv_n = dsta[s + 16]; }

        // ---- 16 scattered X-row loads issued FIRST: in flight across MFMA A+B ----
        XLOAD(0)  XLOAD(1)  XLOAD(2)  XLOAD(3)
        XLOAD(4)  XLOAD(5)  XLOAD(6)  XLOAD(7)
        XLOAD(8)  XLOAD(9)  XLOAD(10) XLOAD(11)
        XLOAD(12) XLOAD(13) XLOAD(14) XLOAD(15)

        // ---- pack ea (waits only the ea loads — oldest outstanding) ----
        uint4 eau = make_uint4(0u, 0u, 0u, 0u);
        if (quad < 2) {
            eau.x = pkbf16(er0.x, er0.y); eau.y = pkbf16(er0.z, er0.w);
            eau.z = pkbf16(er1.x, er1.y); eau.w = pkbf16(er1.z, er1.w);
        }
        const bf16x8 eaf = __builtin_bit_cast(bf16x8, eau);

        // ---- edge MLP layer A ----
        __builtin_amdgcn_s_setprio(1);
        f32x4 c1[4];
#pragma unroll
        for (int tt = 0; tt < 4; tt++) {
            f32x4 ci = {b1v[tt].x, b1v[tt].y, b1v[tt].z, b1v[tt].w};
            c1[tt] = __builtin_amdgcn_mfma_f32_16x16x32_bf16(w1f[tt], eaf, ci, 0, 0, 0);
        }
        __builtin_amdgcn_s_setprio(0);
        bf16x8 a2[2];
#pragma unroll
        for (int ka = 0; ka < 2; ka++) {
            uint4 au;
            au.x = pkbf16(fmaxf(c1[2 * ka][0], 0.f),     fmaxf(c1[2 * ka][1], 0.f));
            au.y = pkbf16(fmaxf(c1[2 * ka][2], 0.f),     fmaxf(c1[2 * ka][3], 0.f));
            au.z = pkbf16(fmaxf(c1[2 * ka + 1][0], 0.f), fmaxf(c1[2 * ka + 1][1], 0.f));
            au.w = pkbf16(fmaxf(c1[2 * ka + 1][2], 0.f), fmaxf(c1[2 * ka + 1][3], 0.f));
            a2[ka] = __builtin_bit_cast(bf16x8, au);
        }

        // ---- edge MLP layer B, V-frags streamed; spill to LDS ----
        __builtin_amdgcn_s_setprio(1);
        if constexpr (PK) {
            const unsigned int xr = (unsigned int)((quad & 1) << 4);
#pragma unroll
            for (int nt = 0; nt < 6; nt++) {
                const bf16x8 va0 = *(const bf16x8*)(vfrag + ((nt * 2 + 0) * 64 + lane) * 8);
                const bf16x8 va1 = *(const bf16x8*)(vfrag + ((nt * 2 + 1) * 64 + lane) * 8);
                f32x4 ca = {b2v[nt], b2v[nt], b2v[nt], b2v[nt]};
                ca = __builtin_amdgcn_mfma_f32_16x16x32_bf16(a2[0], va0, ca, 0, 0, 0);
                ca = __builtin_amdgcn_mfma_f32_16x16x32_bf16(a2[1], va1, ca, 0, 0, 0);
                const bf16x8 vb0 = *(const bf16x8*)(vfrag + (((nt + 6) * 2 + 0) * 64 + lane) * 8);
                const bf16x8 vb1 = *(const bf16x8*)(vfrag + (((nt + 6) * 2 + 1) * 64 + lane) * 8);
                f32x4 cb = {b2v[nt + 6], b2v[nt + 6], b2v[nt + 6], b2v[nt + 6]};
                cb = __builtin_amdgcn_mfma_f32_16x16x32_bf16(a2[0], vb0, cb, 0, 0, 0);
                cb = __builtin_amdgcn_mfma_f32_16x16x32_bf16(a2[1], vb1, cb, 0, 0, 0);
#pragma unroll
                for (int r = 0; r < 4; r++)
                    Lu[(quad * 4 + r) * SW + (((unsigned)(nt * 16 + col)) ^ xr)] =
                        pkbf16(ca[r], cb[r]);
            }
        } else {
#pragma unroll
            for (int nt = 0; nt < NT; nt++) {
                const bf16x8 v0 = *(const bf16x8*)(vfrag + ((nt * 2 + 0) * 64 + lane) * 8);
                const bf16x8 v1 = *(const bf16x8*)(vfrag + ((nt * 2 + 1) * 64 + lane) * 8);
                f32x4 c = {b2v[nt], b2v[nt], b2v[nt], b2v[nt]};
                c = __builtin_amdgcn_mfma_f32_16x16x32_bf16(a2[0], v0, c, 0, 0, 0);
                c = __builtin_amdgcn_mfma_f32_16x16x32_bf16(a2[1], v1, c, 0, 0, 0);
#pragma unroll
                for (int r = 0; r < 4; r++)
                    Lf[(quad * 4 + r) * SW + nt * 16 + col] = c[r];
            }
        }
        __builtin_amdgcn_s_setprio(0);

        // ---- issue NEXT tile's edge_attr raw loads: covered by the walk ----
        if (ti + 1 < CT && quad < 2) {
            const int en = se_n.y;
            er0 = *(const float4*)(edge_attr + (size_t)en * 16 + quad * 8);
            er1 = *(const float4*)(edge_attr + (size_t)en * 16 + quad * 8 + 4);
        }

        // ---- segmented walk: LDS + VALU; dst via readlane (SALU) ----
        WSTEP(0)  WSTEP(1)  WSTEP(2)  WSTEP(3)
        WSTEP(4)  WSTEP(5)  WSTEP(6)  WSTEP(7)
        WSTEP(8)  WSTEP(9)  WSTEP(10) WSTEP(11)
        WSTEP(12) WSTEP(13) WSTEP(14) WSTEP(15)

        se = se_n; dv = dv_n;
    }
    do_flush(true);   // final open segment may continue into the next chunk
}
#undef XLOAD
#undef WSTEP

// ---------------- node MLP layer 1 via MFMA (16 nodes per wave) ----------------
__global__ __launch_bounds__(256) void mlp1_mfma_kernel(
    const float* __restrict__ x, const float* __restrict__ agg1,
    const unsigned short* __restrict__ fr2, const float* __restrict__ c1_b1,
    const float* __restrict__ fw, float* __restrict__ h1)
{
    const int lane = threadIdx.x & 63, wid = threadIdx.x >> 6;
    const int tile = blockIdx.x * 4 + wid;
    if (tile >= NTILES) return;
    const int col = lane & 15, quad = lane >> 4;
    const int node = tile * 16 + col;

    const float4 xa = *(const float4*)(x + (size_t)node * 32 + quad * 8);
    const float4 xb = *(const float4*)(x + (size_t)node * 32 + quad * 8 + 4);

    f32x4 c2[4];
#pragma unroll
    for (int b = 0; b < 4; b++) {
        const float ub = fw[F_UB1 + b * 16 + col];
        c2[b] = {ub, ub, ub, ub};
    }
#pragma unroll
    for (int i = 0; i < 3; i++) {
        const float4 a0 = *(const float4*)(agg1 + (size_t)node * 96 + i * 32 + quad * 8);
        const float4 a1 = *(const float4*)(agg1 + (size_t)node * 96 + i * 32 + quad * 8 + 4);
        uint4 iu;
        iu.x = pkbf16(xa.x + a0.x, xa.y + a0.y);
        iu.y = pkbf16(xa.z + a0.z, xa.w + a0.w);
        iu.z = pkbf16(xb.x + a1.x, xb.y + a1.y);
        iu.w = pkbf16(xb.z + a1.z, xb.w + a1.w);
        const bf16x8 inf = __builtin_bit_cast(bf16x8, iu);

        f32x4 c1[4];
#pragma unroll
        for (int tt = 0; tt < 4; tt++) {
            const bf16x8 wf = *(const bf16x8*)(fr2 + FR3_M1W + ((i * 4 + tt) * 64 + lane) * 8);
            const float4 bi = *(const float4*)(c1_b1 + i * 64 + tt * 16 + quad * 4);
            f32x4 ci = {bi.x, bi.y, bi.z, bi.w};
            c1[tt] = __builtin_amdgcn_mfma_f32_16x16x32_bf16(wf, inf, ci, 0, 0, 0);
        }
        bf16x8 a2[2];
#pragma unroll
        for (int ka = 0; ka < 2; ka++) {
            uint4 au;
            au.x = pkbf16(fmaxf(c1[2 * ka][0], 0.f),     fmaxf(c1[2 * ka][1], 0.f));
            au.y = pkbf16(fmaxf(c1[2 * ka][2], 0.f),     fmaxf(c1[2 * ka][3], 0.f));
            au.z = pkbf16(fmaxf(c1[2 * ka + 1][0], 0.f), fmaxf(c1[2 * ka + 1][1], 0.f));
            au.w = pkbf16(fmaxf(c1[2 * ka + 1][2], 0.f), fmaxf(c1[2 * ka + 1][3], 0.f));
            a2[ka] = __builtin_bit_cast(bf16x8, au);
        }
#pragma unroll
        for (int b = 0; b < 4; b++)
#pragma unroll
            for (int ka = 0; ka < 2; ka++) {
                const bf16x8 uf = *(const bf16x8*)(fr2 + FR3_M1U + (((i * 4 + b) * 2 + ka) * 64 + lane) * 8);
                c2[b] = __builtin_amdgcn_mfma_f32_16x16x32_bf16(a2[ka], uf, c2[b], 0, 0, 0);
            }
    }
    const int rowb = tile * 16 + quad * 4;
#pragma unroll
    for (int b = 0; b < 4; b++)
#pragma unroll
        for (int r = 0; r < 4; r++)
            h1[(size_t)(rowb + r) * 64 + b * 16 + col] = fmaxf(c2[b][r], 0.f);
}

// ---------------- node MLP layer 2 via MFMA (16 nodes per wave) ----------------
__global__ __launch_bounds__(256) void mlp2_mfma_kernel(
    const float* __restrict__ h1, const float* __restrict__ agg2,
    const unsigned short* __restrict__ fr2, const float* __restrict__ c2_b1,
    const float* __restrict__ fw, float* __restrict__ h2)
{
    const int lane = threadIdx.x & 63, wid = threadIdx.x >> 6;
    const int tile = blockIdx.x * 4 + wid;
    if (tile >= NTILES) return;
    const int col = lane & 15, quad = lane >> 4;
    const int node = tile * 16 + col;

    float4 hv[4];
#pragma unroll
    for (int p = 0; p < 4; p++)
        hv[p] = *(const float4*)(h1 + (size_t)node * 64 + (p >> 1) * 32 + quad * 8 + (p & 1) * 4);

    f32x4 c2[4];
#pragma unroll
    for (int b = 0; b < 4; b++) {
        const float ub = fw[F_UB2 + b * 16 + col];
        c2[b] = {ub, ub, ub, ub};
    }
#pragma unroll
    for (int i = 0; i < 3; i++) {
        bf16x8 inf[2];
#pragma unroll
        for (int ka = 0; ka < 2; ka++) {
            const float4 a0 = *(const float4*)(agg2 + (size_t)node * 192 + i * 64 + ka * 32 + quad * 8);
            const float4 a1 = *(const float4*)(agg2 + (size_t)node * 192 + i * 64 + ka * 32 + quad * 8 + 4);
            const float4 h0 = hv[ka * 2], h1v = hv[ka * 2 + 1];
            uint4 iu;
            iu.x = pkbf16(h0.x + a0.x, h0.y + a0.y);
            iu.y = pkbf16(h0.z + a0.z, h0.w + a0.w);
            iu.z = pkbf16(h1v.x + a1.x, h1v.y + a1.y);
            iu.w = pkbf16(h1v.z + a1.z, h1v.w + a1.w);
            inf[ka] = __builtin_bit_cast(bf16x8, iu);
        }
        f32x4 c1[4];
#pragma unroll
        for (int tt = 0; tt < 4; tt++) {
            const bf16x8 wf0 = *(const bf16x8*)(fr2 + FR3_M2W + (((i * 4 + tt) * 2 + 0) * 64 + lane) * 8);
            const bf16x8 wf1 = *(const bf16x8*)(fr2 + FR3_M2W + (((i * 4 + tt) * 2 + 1) * 64 + lane) * 8);
            const float4 bi = *(const float4*)(c2_b1 + i * 64 + tt * 16 + quad * 4);
            f32x4 ci = {bi.x, bi.y, bi.z, bi.w};
            ci = __builtin_amdgcn_mfma_f32_16x16x32_bf16(wf0, inf[0], ci, 0, 0, 0);
            c1[tt] = __builtin_amdgcn_mfma_f32_16x16x32_bf16(wf1, inf[1], ci, 0, 0, 0);
        }
        bf16x8 a2[2];
#pragma unroll
        for (int ka = 0; ka < 2; ka++) {
            uint4 au;
            au.x = pkbf16(fmaxf(c1[2 * ka][0], 0.f),     fmaxf(c1[2 * ka][1], 0.f));
            au.y = pkbf16(fmaxf(c1[2 * ka][2], 0.f),     fmaxf(c1[2 * ka][3], 0.f));
            au.z = pkbf16(fmaxf(c1[2 * ka + 1][0], 0.f), fmaxf(c1[2 * ka + 1][1], 0.f));
            au.w = pkbf16(fmaxf(c1[2 * ka + 1][2], 0.f), fmaxf(c1[2 * ka + 1][3], 0.f));
            a2[ka] = __builtin_bit_cast(bf16x8, au);
        }
#pragma unroll
        for (int b = 0; b < 4; b++)
#pragma unroll
            for (int ka = 0; ka < 2; ka++) {
                const bf16x8 uf = *(const bf16x8*)(fr2 + FR3_M2U + (((i * 4 + b) * 2 + ka) * 64 + lane) * 8);
                c2[b] = __builtin_amdgcn_mfma_f32_16x16x32_bf16(a2[ka], uf, c2[b], 0, 0, 0);
            }
    }
    const int rowb = tile * 16 + quad * 4;
#pragma unroll
    for (int b = 0; b < 4; b++)
#pragma unroll
        for (int r = 0; r < 4; r++)
            h2[(size_t)(rowb + r) * 64 + b * 16 + col] = fmaxf(c2[b][r], 0.f);
}

// ---------------- pooling + head (fused; batch is sorted) ----------------
__global__ __launch_bounds__(256) void pool_kernel(
    const float* __restrict__ h2, const int* __restrict__ batch,
    const float* __restrict__ u, const float* __restrict__ fc_w,
    const float* __restrict__ fc_b, float* __restrict__ out)
{
    __shared__ float red[256];
    const int g = blockIdx.x, t = threadIdx.x;
    int lo = 0, hi = N_NODES;
    while (lo < hi) { int m = (lo + hi) >> 1; if (batch[m] < g) lo = m + 1; else hi = m; }
    int lo2 = lo, hi2 = N_NODES;
    while (lo2 < hi2) { int m = (lo2 + hi2) >> 1; if (batch[m] < g + 1) lo2 = m + 1; else hi2 = m; }

    const int col = t & 63, ch = t >> 6;
    float s = 0.f;
    for (int idx = lo + ch; idx < lo2; idx += 4) s += h2[(size_t)idx * 64 + col];
    red[t] = s;
    __syncthreads();
    if (t < 64) red[t] = red[t] + red[64 + t] + red[128 + t] + red[192 + t];
    __syncthreads();
    if (t == 0) {
        const float inv = 1.f / fmaxf((float)(lo2 - lo), 1.f);
        float sv = fc_b[0];
        for (int j = 0; j < 64; j++) sv = fmaf(red[j] * inv, fc_w[j], sv);
        for (int k = 0; k < 32; k++) sv = fmaf(u[(size_t)g * 32 + k], fc_w[64 + k], sv);
        out[g] = sv;
    }
}

extern "C" void kernel_launch(void* const* d_in, const int* in_sizes, int n_in,
                              void* d_out, int out_size, void* d_ws, size_t ws_size,
                              hipStream_t stream) {
    (void)in_sizes; (void)n_in; (void)out_size; (void)ws_size;
    const float* x        = (const float*)d_in[0];
    const float* edge_attr= (const float*)d_in[1];
    const float* u        = (const float*)d_in[2];
    const float* em1_w1   = (const float*)d_in[3];
    const float* em1_b1   = (const float*)d_in[4];
    const float* em1_w2   = (const float*)d_in[5];
    const float* em1_b2   = (const float*)d_in[6];
    const float* em2_w1   = (const float*)d_in[7];
    const float* em2_b1   = (const float*)d_in[8];
    const float* em2_w2   = (const float*)d_in[9];
    const float* em2_b2   = (const float*)d_in[10];
    const float* c1_lin_w = (const float*)d_in[11];
    const float* c1_lin_b = (const float*)d_in[12];
    const float* c1_w1    = (const float*)d_in[13];
    const float* c1_b1    = (const float*)d_in[14];
    const float* c1_w2    = (const float*)d_in[15];
    const float* c1_b2    = (const float*)d_in[16];
    const float* c2_lin_w = (const float*)d_in[17];
    const float* c2_lin_b = (const float*)d_in[18];
    const float* c2_w1    = (const float*)d_in[19];
    const float* c2_b1    = (const float*)d_in[20];
    const float* c2_w2    = (const float*)d_in[21];
    const float* c2_b2    = (const float*)d_in[22];
    const float* lin1_w   = (const float*)d_in[23];
    const float* lin1_b   = (const float*)d_in[24];
    const float* lin2_w   = (const float*)d_in[25];
    const float* lin2_b   = (const float*)d_in[26];
    const float* fc_w     = (const float*)d_in[27];
    const float* fc_b     = (const float*)d_in[28];
    const int*   ei       = (const int*)d_in[29];
    const int*   batch    = (const int*)d_in[30];

    char* wsb = (char*)d_ws;
    int*   cnt  = (int*)(wsb + B_CNT);
    int*   off  = (int*)(wsb + B_OFF);
    int*   cur  = (int*)(wsb + B_CUR);
    int*   bsum = (int*)(wsb + B_BSUM);
    int2*  sedge= (int2*)(wsb + B_SEDGE);
    int*   dsta = (int*)(wsb + B_DSTA);
    float* agg  = (float*)(wsb + B_AGG);    // [N][96] for layer1, [N][192] for layer2
    float* h1   = (float*)(wsb + B_H1);
    float* h2   = (float*)(wsb + B_H2);
    float* fw   = (float*)(wsb + B_FOLD);
    unsigned short* fr  = (unsigned short*)(wsb + B_FRAG);
    unsigned short* fr2 = (unsigned short*)(wsb + B_FR2);
    float* out  = (float*)d_out;

    (void)hipMemsetAsync(d_ws, 0, ZERO_BYTES, stream);   // histogram counters only

    fold_kernel<<<(FOLD_TOTAL + 255) / 256, 256, 0, stream>>>(
        em1_w2, em1_b2, em2_w2, em2_b2, c1_lin_w, c1_lin_b, c2_lin_w, c2_lin_b,
        c1_w2, c1_b2, c2_w2, c2_b2, lin1_w, lin1_b, lin2_w, lin2_b, fw);
    fold2_kernel<<<(FOLD2_TOTAL + 255) / 256, 256, 0, stream>>>(em1_w1, em2_w1, fw, fr);
    fold3_kernel<<<(FOLD3_TOTAL + 255) / 256, 256, 0, stream>>>(c1_w1, c2_w1, fw, fr2);

    // counting sort by dst
    hist_kernel<<<N_EDGES / 256, 256, 0, stream>>>(ei, cnt);
    scan1_kernel<<<196, 256, 0, stream>>>(cnt, off, bsum);
    scan2_kernel<<<1, 256, 0, stream>>>(bsum);
    scan3_kernel<<<196, 256, 0, stream>>>(off, bsum, cur);
    scatter_kernel<<<N_EDGES / 256, 256, 0, stream>>>(ei, cur, sedge, dsta);

    // layer 1: fused edge MLP + segmented gather (q never hits HBM)
    (void)hipMemsetAsync(wsb + B_AGG, 0, (size_t)N_NODES * 96 * 4, stream);
    fused_edge_gather<6, 32><<<NCHUNKS, 64, 0, stream>>>(
        edge_attr, sedge, dsta, fr + FR_W1E1, em1_b1, fr + FR_V1, fw + F_B1F, x, agg, NCHUNKS);
    mlp1_mfma_kernel<<<(NTILES + 3) / 4, 256, 0, stream>>>(x, agg, fr2, c1_b1, fw, h1);

    // layer 2
    (void)hipMemsetAsync(wsb + B_AGG, 0, (size_t)N_NODES * 192 * 4, stream);
    fused_edge_gather<12, 64><<<NCHUNKS, 64, 0, stream>>>(
        edge_attr, sedge, dsta, fr + FR_W1E2, em2_b1, fr + FR_V2, fw + F_B2F, h1, agg, NCHUNKS);
    mlp2_mfma_kernel<<<(NTILES + 3) / 4, 256, 0, stream>>>(h1, agg, fr2, c2_b1, fw, h2);

    // pooling + head (fused)
    pool_kernel<<<N_GRAPHS, 256, 0, stream>>>(h2, batch, u, fc_w, fc_b, out);
}